// Round 7
// baseline (846.835 us; speedup 1.0000x reference)
//
#include <hip/hip_runtime.h>
#include <hip/hip_fp16.h>

#define NNODES 100000
#define NEDGES 1600000
#define NGRAPH 512
#define DIM    100
#define DP     128
#define EPSBN  1e-5f
#define NBUK   ((NNODES + 255) >> 8)   // 391 dst-buckets of 256 nodes
#define BINCH  8192                    // edges per bin block

typedef _Float16 half8 __attribute__((ext_vector_type(8)));
typedef float floatx4 __attribute__((ext_vector_type(4)));

// ---------------- degree histogram ----------------
__global__ void hist_kernel(const int* __restrict__ dst, int* __restrict__ hist, int e) {
    int i = blockIdx.x * blockDim.x + threadIdx.x;
    if (i < e) atomicAdd(&hist[dst[i]], 1);
}

// ---------------- dinv ----------------
__global__ void dinv_kernel(const int* __restrict__ hist, float* __restrict__ dsl,
                            float* __restrict__ dnsl, int n) {
    int i = blockIdx.x * blockDim.x + threadIdx.x;
    if (i >= n) return;
    float c = (float)hist[i];
    dsl[i]  = rsqrtf(c + 1.0f);
    dnsl[i] = (c > 0.0f) ? rsqrtf(c) : 0.0f;
}

// ---------------- two-level exclusive scan ----------------
__global__ void scan1_kernel(const int* __restrict__ hist, int* __restrict__ off,
                             int* __restrict__ partials, int n) {
    __shared__ int s[256];
    int i = blockIdx.x * 256 + threadIdx.x;
    int v = (i < n) ? hist[i] : 0;
    s[threadIdx.x] = v; __syncthreads();
    for (int o = 1; o < 256; o <<= 1) {
        int t = (threadIdx.x >= o) ? s[threadIdx.x - o] : 0;
        __syncthreads();
        s[threadIdx.x] += t;
        __syncthreads();
    }
    if (i < n) off[i] = s[threadIdx.x] - v;
    if (threadIdx.x == 255) partials[blockIdx.x] = s[255];
}

__global__ void scan2_kernel(int* __restrict__ partials, int nb) {
    __shared__ int s[512];
    int v = (threadIdx.x < nb) ? partials[threadIdx.x] : 0;
    s[threadIdx.x] = v; __syncthreads();
    for (int o = 1; o < 512; o <<= 1) {
        int t = (threadIdx.x >= o) ? s[threadIdx.x - o] : 0;
        __syncthreads();
        s[threadIdx.x] += t;
        __syncthreads();
    }
    if (threadIdx.x < nb) partials[threadIdx.x] = s[threadIdx.x] - v;
}

__global__ void scan3_kernel(int* __restrict__ off, const int* __restrict__ partials,
                             int* __restrict__ bcursor, int n, int e_total) {
    int i = blockIdx.x * 256 + threadIdx.x;
    if (i < n) {
        int v = off[i] + partials[blockIdx.x];
        off[i] = v;
        if ((i & 255) == 0) bcursor[i >> 8] = v;
    }
    if (i == 0) off[n] = e_total;
}

// ---------------- pass 1: bin (src,dst) pairs bucket-major ----------------
__global__ __launch_bounds__(256) void bin_kernel(
        const int* __restrict__ src, const int* __restrict__ dst,
        int* __restrict__ bcursor, int2* __restrict__ gpairs, int e) {
    __shared__ int2 lpairs[BINCH];
    __shared__ int lcount[NBUK], lstart[NBUK], lcur[NBUK], gbase[NBUK];
    int tid = threadIdx.x;
    int base = blockIdx.x * BINCH;
    int m = e - base; if (m > BINCH) m = BINCH;

    for (int b = tid; b < NBUK; b += 256) lcount[b] = 0;
    __syncthreads();

    for (int j = tid; j < m; j += 256)
        atomicAdd(&lcount[dst[base + j] >> 8], 1);
    __syncthreads();

    if (tid == 0) {
        int acc = 0;
        for (int b = 0; b < NBUK; b++) {
            lstart[b] = acc;
            lcur[b] = acc;
            acc += lcount[b];
        }
    }
    __syncthreads();

    for (int b = tid; b < NBUK; b += 256)
        gbase[b] = atomicAdd(&bcursor[b], lcount[b]);
    for (int j = tid; j < m; j += 256) {
        int s = src[base + j], d = dst[base + j];
        int p = atomicAdd(&lcur[d >> 8], 1);
        lpairs[p] = make_int2(s, d);
    }
    __syncthreads();

    for (int j = tid; j < m; j += 256) {
        int2 pr = lpairs[j];
        int b = pr.y >> 8;
        gpairs[gbase[b] + (j - lstart[b])] = pr;
    }
}

// ---------------- pass 2: within-bucket scatter ----------------
__global__ __launch_bounds__(256) void bucket_scatter_kernel(
        const int2* __restrict__ gpairs, const int* __restrict__ off,
        int* __restrict__ ssorted, int n) {
    __shared__ int cur[256];
    int b = blockIdx.x, tid = threadIdx.x;
    int node0 = b << 8;
    int nn = n - node0; if (nn > 256) nn = 256;
    if (tid < nn) cur[tid] = off[node0 + tid];
    __syncthreads();
    int e0 = off[node0];
    int e1 = off[(node0 + nn < n) ? node0 + nn : n];
    for (int j = e0 + tid; j < e1; j += 256) {
        int2 pr = gpairs[j];
        int p = atomicAdd(&cur[pr.y & 255], 1);
        ssorted[p] = pr.x;
    }
}

// ---------------- prescale rows to fp16 ----------------
__global__ void prescale_kernel(const float* __restrict__ x, const float* __restrict__ d,
                                __half* __restrict__ yh, int n) {
    long i = (long)blockIdx.x * blockDim.x + threadIdx.x;
    if (i >= (long)n * 32) return;
    int row = (int)(i >> 5);
    float s = d[row];
    float4 v = ((const float4*)x)[i];
    __half2 p01 = __floats2half2_rn(v.x * s, v.y * s);
    __half2 p23 = __floats2half2_rn(v.z * s, v.w * s);
    uint2 u;
    u.x = *(unsigned int*)&p01;
    u.y = *(unsigned int*)&p23;
    ((uint2*)yh)[i] = u;
}

// ---------------- propagation: one wave per node, fp16 rows, fp32 acc, fp16 out ----------------
__global__ __launch_bounds__(256) void prop_kernel(
        const __half* __restrict__ pre, const int* __restrict__ ssorted,
        const int* __restrict__ off, const float* __restrict__ dinv,
        __half* __restrict__ outH, int n, int selfloop) {
    int wave = (blockIdx.x * blockDim.x + threadIdx.x) >> 6;
    int lane = threadIdx.x & 63;
    if (wave >= n) return;
    int e0 = off[wave], e1 = off[wave + 1];
    int deg = e1 - e0;
    int half_id = lane >> 5;
    int l32  = lane & 31;
    int c0 = l32 * 4;

    float4 acc = make_float4(0.f, 0.f, 0.f, 0.f);

    auto addrow = [&](int s, float4& a) {
        uint2 u = *(const uint2*)&pre[(long)s * DP + c0];
        __half2 h01 = *(__half2*)&u.x;
        __half2 h23 = *(__half2*)&u.y;
        float2 f01 = __half22float2(h01);
        float2 f23 = __half22float2(h23);
        a.x += f01.x; a.y += f01.y; a.z += f23.x; a.w += f23.y;
    };

    for (int base = 0; base < deg; base += 64) {
        int m = deg - base; if (m > 64) m = 64;
        int sidx = (lane < m) ? ssorted[e0 + base + lane] : 0;
        int j = 0;
        for (; j + 8 <= m; j += 8) {
            int sA = __shfl(sidx, j + half_id);
            int sB = __shfl(sidx, j + 2 + half_id);
            int sC = __shfl(sidx, j + 4 + half_id);
            int sD = __shfl(sidx, j + 6 + half_id);
            uint2 uA = *(const uint2*)&pre[(long)sA * DP + c0];
            uint2 uB = *(const uint2*)&pre[(long)sB * DP + c0];
            uint2 uC = *(const uint2*)&pre[(long)sC * DP + c0];
            uint2 uD = *(const uint2*)&pre[(long)sD * DP + c0];
            float2 a0 = __half22float2(*(__half2*)&uA.x), a1 = __half22float2(*(__half2*)&uA.y);
            float2 b0 = __half22float2(*(__half2*)&uB.x), b1 = __half22float2(*(__half2*)&uB.y);
            float2 c0f = __half22float2(*(__half2*)&uC.x), c1 = __half22float2(*(__half2*)&uC.y);
            float2 d0 = __half22float2(*(__half2*)&uD.x), d1 = __half22float2(*(__half2*)&uD.y);
            acc.x += (a0.x + b0.x) + (c0f.x + d0.x);
            acc.y += (a0.y + b0.y) + (c0f.y + d0.y);
            acc.z += (a1.x + b1.x) + (c1.x + d1.x);
            acc.w += (a1.y + b1.y) + (c1.y + d1.y);
        }
        for (; j + 2 <= m; j += 2) {
            int s = __shfl(sidx, j + half_id);
            addrow(s, acc);
        }
        if (j < m) {
            int s = __shfl(sidx, j);
            if (half_id == 0) addrow(s, acc);
        }
    }

    acc.x += __shfl(acc.x, l32 + 32);
    acc.y += __shfl(acc.y, l32 + 32);
    acc.z += __shfl(acc.z, l32 + 32);
    acc.w += __shfl(acc.w, l32 + 32);

    if (half_id == 0) {
        float dn = dinv[wave];
        if (selfloop) addrow(wave, acc);
        __half2 p01 = __floats2half2_rn(dn * acc.x, dn * acc.y);
        __half2 p23 = __floats2half2_rn(dn * acc.z, dn * acc.w);
        uint2 u;
        u.x = *(unsigned int*)&p01;
        u.y = *(unsigned int*)&p23;
        *(uint2*)&outH[(long)wave * DP + c0] = u;
    }
}

// ---------------- MFMA matmul: C[M,128] = op(A[M,128]fp16 @ W[K,Kout]) ----------------
// 4 waves/block, wave w does rows [blk*64+w*16, +16), all 128 cols.
// A-frag: A[m=lane&15][k=quad*8+j]; B-frag: W[k=quad*8+j][n=lane&15];
// C/D: col=lane&15, row=quad*4+reg  (HW-verified layouts)
__global__ __launch_bounds__(256) void matmul_mfma_kernel(
        const __half* __restrict__ A, const float* __restrict__ W,
        const float* __restrict__ bias, const __half* __restrict__ addendH,
        const float* __restrict__ rowscale,
        float* __restrict__ C, __half* __restrict__ Ch,
        int M, int K, int Kout, int relu) {
    __shared__ _Float16 Wl[128 * 136];   // transposed [n][k], stride 136 (34 KB)
    int tid = threadIdx.x;

    for (int idx = tid; idx < 128 * 128; idx += 256) {
        int k = idx >> 7, n = idx & 127;
        float v = (k < K && n < Kout) ? W[k * Kout + n] : 0.f;
        Wl[n * 136 + k] = (_Float16)v;
    }
    __syncthreads();

    int wave = tid >> 6;
    int lane = tid & 63;
    int m16 = lane & 15;
    int quad = lane >> 4;
    long row0 = (long)blockIdx.x * 64 + wave * 16;

    half8 af[4];
    {
        long ar = row0 + m16; if (ar >= M) ar = M - 1;
        const _Float16* Ap = (const _Float16*)&A[ar * DP + quad * 8];
#pragma unroll
        for (int k0 = 0; k0 < 4; k0++)
            af[k0] = *(const half8*)(Ap + k0 * 32);
    }

    floatx4 acc[8];
#pragma unroll
    for (int t = 0; t < 8; t++) acc[t] = (floatx4){0.f, 0.f, 0.f, 0.f};

#pragma unroll
    for (int t = 0; t < 8; t++) {
        const _Float16* Wp = &Wl[(t * 16 + m16) * 136 + quad * 8];
#pragma unroll
        for (int k0 = 0; k0 < 4; k0++) {
            half8 bf = *(const half8*)(Wp + k0 * 32);
            acc[t] = __builtin_amdgcn_mfma_f32_16x16x32_f16(af[k0], bf, acc[t], 0, 0, 0);
        }
    }

#pragma unroll
    for (int t = 0; t < 8; t++) {
        int col = t * 16 + m16;
        float bv = (bias && col < Kout) ? bias[col] : 0.f;
#pragma unroll
        for (int r = 0; r < 4; r++) {
            long row = row0 + quad * 4 + r;
            if (row >= M) continue;
            float v = acc[t][r] + bv;
            if (addendH) v += (float)addendH[row * DP + col];
            if (relu) v = fmaxf(v, 0.f);
            if (rowscale) v *= rowscale[row];
            if (Ch) Ch[row * DP + col] = (__half)v;
            else    C[row * DP + col] = v;
        }
    }
}

// ---------------- batchnorm stats ----------------
__global__ void bn_stats_kernel(const float* __restrict__ h, float* __restrict__ sum,
                                float* __restrict__ sq, int n) {
    int col = threadIdx.x;
    float s = 0.f, q = 0.f;
    for (int row = blockIdx.x; row < n; row += gridDim.x) {
        float v = h[(long)row * DP + col];
        s += v;
        q += v * v;
    }
    atomicAdd(&sum[col], s);
    atomicAdd(&sq[col], q);
}

// ---------------- batchnorm apply -> fp16 h ----------------
__global__ void bn_apply_kernel(const float* __restrict__ h, const float* __restrict__ sum,
                                const float* __restrict__ sq, const float* __restrict__ gamma,
                                const float* __restrict__ beta, __half* __restrict__ outH, int n) {
    long i = (long)blockIdx.x * blockDim.x + threadIdx.x;
    if (i >= (long)n * DP) return;
    int c = (int)(i & 127);
    float v = 0.f;
    if (c < DIM) {
        float inv_n = 1.0f / (float)n;
        float mu = sum[c] * inv_n;
        float var = sq[c] * inv_n - mu * mu;
        float rs = rsqrtf(var + EPSBN);
        v = (h[i] - mu) * rs * gamma[c] + beta[c];
    }
    outH[i] = (__half)v;
}

// ---------------- graph boundaries ----------------
__global__ void gbounds_kernel(const int* __restrict__ batch, int* __restrict__ gstart, int n) {
    int g = threadIdx.x;
    int lo = 0, hi = n;
    while (lo < hi) {
        int mid = (lo + hi) >> 1;
        if (batch[mid] < g) lo = mid + 1; else hi = mid;
    }
    gstart[g] = lo;
    if (g == 0) gstart[NGRAPH] = n;
}

// ---------------- global add pool ----------------
__global__ __launch_bounds__(512) void pool_kernel(const float* __restrict__ a,
                                                   const int* __restrict__ gstart,
                                                   float* __restrict__ g) {
    __shared__ float red[512];
    int b = blockIdx.x, tid = threadIdx.x;
    int col = tid & 127;
    int quarter = tid >> 7;
    int lo = gstart[b], hi = gstart[b + 1];
    float s = 0.f;
    for (int r = lo + quarter; r < hi; r += 4)
        s += a[(long)r * DP + col];
    red[tid] = s;
    __syncthreads();
    if (tid < 128)
        g[b * DP + tid] = red[tid] + red[tid + 128] + red[tid + 256] + red[tid + 384];
}

// ---------------- fused MLP head ----------------
__global__ __launch_bounds__(256) void mlp_kernel(
        const float* __restrict__ g,
        const float* __restrict__ Wf1, const float* __restrict__ bf1,
        const float* __restrict__ Wf2, const float* __restrict__ bf2,
        const float* __restrict__ Wf3, const float* __restrict__ bf3,
        const float* __restrict__ Wf4, const float* __restrict__ bf4,
        float* __restrict__ out) {
    __shared__ float a0[100], a1[200], a2[300], a3[200], red[256];
    int b = blockIdx.x, tid = threadIdx.x;
    if (tid < 100) a0[tid] = g[b * DP + tid];
    __syncthreads();
    for (int c = tid; c < 200; c += 256) {
        float s = bf1[c];
        for (int k = 0; k < 100; k++) s += a0[k] * Wf1[k * 200 + c];
        a1[c] = fmaxf(s, 0.f);
    }
    __syncthreads();
    for (int c = tid; c < 300; c += 256) {
        float s = bf2[c];
        for (int k = 0; k < 200; k++) s += a1[k] * Wf2[k * 300 + c];
        a2[c] = fmaxf(s, 0.f);
    }
    __syncthreads();
    for (int c = tid; c < 200; c += 256) {
        float s = bf3[c];
        for (int k = 0; k < 300; k++) s += a2[k] * Wf3[k * 200 + c];
        a3[c] = fmaxf(s, 0.f);
    }
    __syncthreads();
    red[tid] = (tid < 200) ? a3[tid] * Wf4[tid] : 0.f;
    __syncthreads();
    for (int o = 128; o > 0; o >>= 1) {
        if (tid < o) red[tid] += red[tid + o];
        __syncthreads();
    }
    if (tid == 0) out[b] = red[0] + bf4[0];
}

extern "C" void kernel_launch(void* const* d_in, const int* in_sizes, int n_in,
                              void* d_out, int out_size, void* d_ws, size_t ws_size,
                              hipStream_t stream) {
    const float* x      = (const float*)d_in[0];
    const int*   src    = (const int*)d_in[1];
    const int*   dst    = (const int*)d_in[2];
    const int*   batch  = (const int*)d_in[3];
    const float* W1     = (const float*)d_in[4];
    const float* b1     = (const float*)d_in[5];
    const float* W2     = (const float*)d_in[6];
    const float* b2     = (const float*)d_in[7];
    const float* gamma  = (const float*)d_in[8];
    const float* beta   = (const float*)d_in[9];
    const float* Wa_init= (const float*)d_in[10];
    const float* Wa_root= (const float*)d_in[11];
    const float* ba     = (const float*)d_in[12];
    const float* Wf1    = (const float*)d_in[13];
    const float* bf1    = (const float*)d_in[14];
    const float* Wf2    = (const float*)d_in[15];
    const float* bf2    = (const float*)d_in[16];
    const float* Wf3    = (const float*)d_in[17];
    const float* bf3    = (const float*)d_in[18];
    const float* Wf4    = (const float*)d_in[19];
    const float* bf4    = (const float*)d_in[20];
    float* out = (float*)d_out;

    const int n = NNODES;
    const int e = NEDGES;

    char* ws = (char*)d_ws;
    auto carve = [&](size_t bytes) -> void* {
        void* p = (void*)ws;
        ws += (bytes + 255) & ~(size_t)255;
        return p;
    };
    float*  bufB    = (float*)carve((size_t)n * DP * 4);    // fp32: h2 / final a
    __half* bufH    = (__half*)carve((size_t)n * DP * 2);   // prop input
    __half* bufHA   = (__half*)carve((size_t)n * DP * 2);   // prop output / matmul A / addend
    __half* bufHB   = (__half*)carve((size_t)n * DP * 2);   // BN'd h fp16
    int*    hist    = (int*)carve((size_t)n * 4);
    int*    off     = (int*)carve((size_t)(n + 1) * 4);
    int*    bcursor = (int*)carve((size_t)NBUK * 4);
    int*    partials= (int*)carve(512 * 4);
    int*    ssorted = (int*)carve((size_t)e * 4);
    int2*   gpairs  = (int2*)carve((size_t)e * 8);
    float*  dinv_sl = (float*)carve((size_t)n * 4);
    float*  dinv_nsl= (float*)carve((size_t)n * 4);
    float*  bnsum   = (float*)carve(DP * 4);
    float*  bnsq    = (float*)carve(DP * 4);
    int*    gstart  = (int*)carve((size_t)(NGRAPH + 1) * 4);
    float*  gpool   = (float*)carve((size_t)NGRAPH * DP * 4);

    const int nb = (n + 255) / 256;

    // ---- build CSR by dst (bucketed two-pass scatter) ----
    hipMemsetAsync(hist, 0, (size_t)n * 4, stream);
    hist_kernel<<<(e + 255) / 256, 256, 0, stream>>>(dst, hist, e);
    dinv_kernel<<<(n + 255) / 256, 256, 0, stream>>>(hist, dinv_sl, dinv_nsl, n);
    scan1_kernel<<<nb, 256, 0, stream>>>(hist, off, partials, n);
    scan2_kernel<<<1, 512, 0, stream>>>(partials, nb);
    scan3_kernel<<<nb, 256, 0, stream>>>(off, partials, bcursor, n, e);
    bin_kernel<<<(e + BINCH - 1) / BINCH, 256, 0, stream>>>(src, dst, bcursor, gpairs, e);
    bucket_scatter_kernel<<<NBUK, 256, 0, stream>>>(gpairs, off, ssorted, n);
    gbounds_kernel<<<1, 512, 0, stream>>>(batch, gstart, n);

    const int prop_blocks = (n + 3) / 4;
    const int mm_blocks = (n + 63) / 64;

    // ---- SGConv 1: pre = x*dinv (fp16); prop; h1' = relu(prop@W1+b1)*dinv -> fp16 ----
    prescale_kernel<<<(int)(((long)n * 32 + 255) / 256), 256, 0, stream>>>(x, dinv_sl, bufH, n);
    prop_kernel<<<prop_blocks, 256, 0, stream>>>(bufH, ssorted, off, dinv_sl, bufHA, n, 1);
    matmul_mfma_kernel<<<mm_blocks, 256, 0, stream>>>(bufHA, W1, b1, nullptr, dinv_sl, nullptr, bufH, n, 128, DIM, 1);

    // ---- SGConv 2: prop on fp16 h1'; h2 = relu(prop@W2+b2) (fp32 for BN) ----
    prop_kernel<<<prop_blocks, 256, 0, stream>>>(bufH, ssorted, off, dinv_sl, bufHA, n, 1);
    matmul_mfma_kernel<<<mm_blocks, 256, 0, stream>>>(bufHA, W2, b2, nullptr, nullptr, bufB, nullptr, n, DIM, DIM, 1);

    // ---- BatchNorm -> fp16 h ----
    hipMemsetAsync(bnsum, 0, DP * 4, stream);
    hipMemsetAsync(bnsq, 0, DP * 4, stream);
    bn_stats_kernel<<<512, 128, 0, stream>>>(bufB, bnsum, bnsq, n);
    bn_apply_kernel<<<(int)(((long)n * DP + 255) / 256), 256, 0, stream>>>(bufB, bnsum, bnsq, gamma, beta, bufHB, n);

    // ---- ARMAConv: t = (h@Wa_init)*dinv_nsl (fp16); prop(no SL) fp16; relu(h@Wa_root+ba+t_prop) ----
    matmul_mfma_kernel<<<mm_blocks, 256, 0, stream>>>(bufHB, Wa_init, nullptr, nullptr, dinv_nsl, nullptr, bufH, n, DIM, DIM, 0);
    prop_kernel<<<prop_blocks, 256, 0, stream>>>(bufH, ssorted, off, dinv_nsl, bufHA, n, 0);
    matmul_mfma_kernel<<<mm_blocks, 256, 0, stream>>>(bufHB, Wa_root, ba, bufHA, nullptr, bufB, nullptr, n, DIM, DIM, 1);

    // ---- global add pool ----
    pool_kernel<<<NGRAPH, 512, 0, stream>>>(bufB, gstart, gpool);

    // ---- MLP head ----
    mlp_kernel<<<NGRAPH, 256, 0, stream>>>(gpool, Wf1, bf1, Wf2, bf2, Wf3, bf3, Wf4, bf4, out);
}

// Round 8
// 805.178 us; speedup vs baseline: 1.0517x; 1.0517x over previous
//
#include <hip/hip_runtime.h>
#include <hip/hip_fp16.h>

#define NNODES 100000
#define NEDGES 1600000
#define NGRAPH 512
#define DIM    100
#define DP     128
#define EPSBN  1e-5f
#define NBUK   ((NNODES + 255) >> 8)   // 391 dst-buckets of 256 nodes
#define BINCH  8192                    // edges per bin block

typedef _Float16 half8 __attribute__((ext_vector_type(8)));
typedef float floatx4 __attribute__((ext_vector_type(4)));

// ---------------- degree histogram ----------------
__global__ void hist_kernel(const int* __restrict__ dst, int* __restrict__ hist, int e) {
    int i = blockIdx.x * blockDim.x + threadIdx.x;
    if (i < e) atomicAdd(&hist[dst[i]], 1);
}

// ---------------- dinv ----------------
__global__ void dinv_kernel(const int* __restrict__ hist, float* __restrict__ dsl,
                            float* __restrict__ dnsl, int n) {
    int i = blockIdx.x * blockDim.x + threadIdx.x;
    if (i >= n) return;
    float c = (float)hist[i];
    dsl[i]  = rsqrtf(c + 1.0f);
    dnsl[i] = (c > 0.0f) ? rsqrtf(c) : 0.0f;
}

// ---------------- two-level exclusive scan ----------------
__global__ void scan1_kernel(const int* __restrict__ hist, int* __restrict__ off,
                             int* __restrict__ partials, int n) {
    __shared__ int s[256];
    int i = blockIdx.x * 256 + threadIdx.x;
    int v = (i < n) ? hist[i] : 0;
    s[threadIdx.x] = v; __syncthreads();
    for (int o = 1; o < 256; o <<= 1) {
        int t = (threadIdx.x >= o) ? s[threadIdx.x - o] : 0;
        __syncthreads();
        s[threadIdx.x] += t;
        __syncthreads();
    }
    if (i < n) off[i] = s[threadIdx.x] - v;
    if (threadIdx.x == 255) partials[blockIdx.x] = s[255];
}

__global__ void scan2_kernel(int* __restrict__ partials, int nb) {
    __shared__ int s[512];
    int v = (threadIdx.x < nb) ? partials[threadIdx.x] : 0;
    s[threadIdx.x] = v; __syncthreads();
    for (int o = 1; o < 512; o <<= 1) {
        int t = (threadIdx.x >= o) ? s[threadIdx.x - o] : 0;
        __syncthreads();
        s[threadIdx.x] += t;
        __syncthreads();
    }
    if (threadIdx.x < nb) partials[threadIdx.x] = s[threadIdx.x] - v;
}

__global__ void scan3_kernel(int* __restrict__ off, const int* __restrict__ partials,
                             int* __restrict__ bcursor, int n, int e_total) {
    int i = blockIdx.x * 256 + threadIdx.x;
    if (i < n) {
        int v = off[i] + partials[blockIdx.x];
        off[i] = v;
        if ((i & 255) == 0) bcursor[i >> 8] = v;
    }
    if (i == 0) off[n] = e_total;
}

// ---------------- pass 1: bin (src,dst) pairs bucket-major ----------------
__global__ __launch_bounds__(256) void bin_kernel(
        const int* __restrict__ src, const int* __restrict__ dst,
        int* __restrict__ bcursor, int2* __restrict__ gpairs, int e) {
    __shared__ int2 lpairs[BINCH];
    __shared__ int lcount[NBUK], lstart[NBUK], lcur[NBUK], gbase[NBUK];
    int tid = threadIdx.x;
    int base = blockIdx.x * BINCH;
    int m = e - base; if (m > BINCH) m = BINCH;

    for (int b = tid; b < NBUK; b += 256) lcount[b] = 0;
    __syncthreads();

    for (int j = tid; j < m; j += 256)
        atomicAdd(&lcount[dst[base + j] >> 8], 1);
    __syncthreads();

    if (tid == 0) {
        int acc = 0;
        for (int b = 0; b < NBUK; b++) {
            lstart[b] = acc;
            lcur[b] = acc;
            acc += lcount[b];
        }
    }
    __syncthreads();

    for (int b = tid; b < NBUK; b += 256)
        gbase[b] = atomicAdd(&bcursor[b], lcount[b]);
    for (int j = tid; j < m; j += 256) {
        int s = src[base + j], d = dst[base + j];
        int p = atomicAdd(&lcur[d >> 8], 1);
        lpairs[p] = make_int2(s, d);
    }
    __syncthreads();

    for (int j = tid; j < m; j += 256) {
        int2 pr = lpairs[j];
        int b = pr.y >> 8;
        gpairs[gbase[b] + (j - lstart[b])] = pr;
    }
}

// ---------------- pass 2: within-bucket scatter ----------------
__global__ __launch_bounds__(256) void bucket_scatter_kernel(
        const int2* __restrict__ gpairs, const int* __restrict__ off,
        int* __restrict__ ssorted, int n) {
    __shared__ int cur[256];
    int b = blockIdx.x, tid = threadIdx.x;
    int node0 = b << 8;
    int nn = n - node0; if (nn > 256) nn = 256;
    if (tid < nn) cur[tid] = off[node0 + tid];
    __syncthreads();
    int e0 = off[node0];
    int e1 = off[(node0 + nn < n) ? node0 + nn : n];
    for (int j = e0 + tid; j < e1; j += 256) {
        int2 pr = gpairs[j];
        int p = atomicAdd(&cur[pr.y & 255], 1);
        ssorted[p] = pr.x;
    }
}

// ---------------- prescale rows to fp16 ----------------
__global__ void prescale_kernel(const float* __restrict__ x, const float* __restrict__ d,
                                __half* __restrict__ yh, int n) {
    long i = (long)blockIdx.x * blockDim.x + threadIdx.x;
    if (i >= (long)n * 32) return;
    int row = (int)(i >> 5);
    float s = d[row];
    float4 v = ((const float4*)x)[i];
    __half2 p01 = __floats2half2_rn(v.x * s, v.y * s);
    __half2 p23 = __floats2half2_rn(v.z * s, v.w * s);
    uint2 u;
    u.x = *(unsigned int*)&p01;
    u.y = *(unsigned int*)&p23;
    ((uint2*)yh)[i] = u;
}

// ---------------- pack W: fp32 [K,Kout] -> fp16 transposed [128,128] ----------------
__global__ void packW_kernel(const float* __restrict__ W, _Float16* __restrict__ Wt,
                             int K, int Kout) {
    int idx = blockIdx.x * 256 + threadIdx.x;
    if (idx >= DP * DP) return;
    int nn = idx >> 7, k = idx & 127;
    float v = (k < K && nn < Kout) ? W[k * Kout + nn] : 0.f;
    Wt[nn * DP + k] = (_Float16)v;
}

// ---------------- propagation: one wave per node, fp16 rows, fp32 acc, fp16 out ----------------
__global__ __launch_bounds__(256) void prop_kernel(
        const __half* __restrict__ pre, const int* __restrict__ ssorted,
        const int* __restrict__ off, const float* __restrict__ dinv,
        __half* __restrict__ outH, int n, int selfloop) {
    int wave = (blockIdx.x * blockDim.x + threadIdx.x) >> 6;
    int lane = threadIdx.x & 63;
    if (wave >= n) return;
    int e0 = off[wave], e1 = off[wave + 1];
    int deg = e1 - e0;
    int half_id = lane >> 5;
    int l32  = lane & 31;
    int c0 = l32 * 4;

    float4 acc = make_float4(0.f, 0.f, 0.f, 0.f);

    auto addrow = [&](int s, float4& a) {
        uint2 u = *(const uint2*)&pre[(long)s * DP + c0];
        __half2 h01 = *(__half2*)&u.x;
        __half2 h23 = *(__half2*)&u.y;
        float2 f01 = __half22float2(h01);
        float2 f23 = __half22float2(h23);
        a.x += f01.x; a.y += f01.y; a.z += f23.x; a.w += f23.y;
    };

    for (int base = 0; base < deg; base += 64) {
        int m = deg - base; if (m > 64) m = 64;
        int sidx = (lane < m) ? ssorted[e0 + base + lane] : 0;
        int j = 0;
        for (; j + 8 <= m; j += 8) {
            int sA = __shfl(sidx, j + half_id);
            int sB = __shfl(sidx, j + 2 + half_id);
            int sC = __shfl(sidx, j + 4 + half_id);
            int sD = __shfl(sidx, j + 6 + half_id);
            uint2 uA = *(const uint2*)&pre[(long)sA * DP + c0];
            uint2 uB = *(const uint2*)&pre[(long)sB * DP + c0];
            uint2 uC = *(const uint2*)&pre[(long)sC * DP + c0];
            uint2 uD = *(const uint2*)&pre[(long)sD * DP + c0];
            float2 a0 = __half22float2(*(__half2*)&uA.x), a1 = __half22float2(*(__half2*)&uA.y);
            float2 b0 = __half22float2(*(__half2*)&uB.x), b1 = __half22float2(*(__half2*)&uB.y);
            float2 c0f = __half22float2(*(__half2*)&uC.x), c1 = __half22float2(*(__half2*)&uC.y);
            float2 d0 = __half22float2(*(__half2*)&uD.x), d1 = __half22float2(*(__half2*)&uD.y);
            acc.x += (a0.x + b0.x) + (c0f.x + d0.x);
            acc.y += (a0.y + b0.y) + (c0f.y + d0.y);
            acc.z += (a1.x + b1.x) + (c1.x + d1.x);
            acc.w += (a1.y + b1.y) + (c1.y + d1.y);
        }
        for (; j + 2 <= m; j += 2) {
            int s = __shfl(sidx, j + half_id);
            addrow(s, acc);
        }
        if (j < m) {
            int s = __shfl(sidx, j);
            if (half_id == 0) addrow(s, acc);
        }
    }

    acc.x += __shfl(acc.x, l32 + 32);
    acc.y += __shfl(acc.y, l32 + 32);
    acc.z += __shfl(acc.z, l32 + 32);
    acc.w += __shfl(acc.w, l32 + 32);

    if (half_id == 0) {
        float dn = dinv[wave];
        if (selfloop) addrow(wave, acc);
        __half2 p01 = __floats2half2_rn(dn * acc.x, dn * acc.y);
        __half2 p23 = __floats2half2_rn(dn * acc.z, dn * acc.w);
        uint2 u;
        u.x = *(unsigned int*)&p01;
        u.y = *(unsigned int*)&p23;
        *(uint2*)&outH[(long)wave * DP + c0] = u;
    }
}

// ---------------- MFMA matmul, no LDS: B-frags from prepacked global Wt (L1-resident) ----------------
// 4 waves/block, wave w does rows [blk*64+w*16, +16), cols 0..127.
// A-frag: A[m=lane&15][k=quad*8+j]; B-frag: Wt[n=col][k] rows; C/D: col=lane&15, row=quad*4+reg
__global__ __launch_bounds__(256) void matmul_mfma_kernel(
        const __half* __restrict__ A, const _Float16* __restrict__ Wt,
        const float* __restrict__ bias, const __half* __restrict__ addendH,
        const float* __restrict__ rowscale,
        float* __restrict__ C, __half* __restrict__ Ch,
        int M, int Kout, int relu) {
    int tid = threadIdx.x;
    int wave = tid >> 6;
    int lane = tid & 63;
    int m16 = lane & 15;
    int quad = lane >> 4;
    long row0 = (long)blockIdx.x * 64 + wave * 16;

    half8 af[4];
    {
        long ar = row0 + m16; if (ar >= M) ar = M - 1;
        const _Float16* Ap = (const _Float16*)&A[ar * DP + quad * 8];
#pragma unroll
        for (int k0 = 0; k0 < 4; k0++)
            af[k0] = *(const half8*)(Ap + k0 * 32);
    }

    floatx4 acc[8];
#pragma unroll
    for (int t = 0; t < 8; t++) acc[t] = (floatx4){0.f, 0.f, 0.f, 0.f};

#pragma unroll
    for (int t = 0; t < 8; t++) {
        const _Float16* Wp = &Wt[(t * 16 + m16) * DP + quad * 8];
#pragma unroll
        for (int k0 = 0; k0 < 4; k0++) {
            half8 bf = *(const half8*)(Wp + k0 * 32);
            acc[t] = __builtin_amdgcn_mfma_f32_16x16x32_f16(af[k0], bf, acc[t], 0, 0, 0);
        }
    }

#pragma unroll
    for (int t = 0; t < 8; t++) {
        int col = t * 16 + m16;
        float bv = (bias && col < Kout) ? bias[col] : 0.f;
#pragma unroll
        for (int r = 0; r < 4; r++) {
            long row = row0 + quad * 4 + r;
            if (row >= M) continue;
            float v = acc[t][r] + bv;
            if (addendH) v += (float)addendH[row * DP + col];
            if (relu) v = fmaxf(v, 0.f);
            if (rowscale) v *= rowscale[row];
            if (Ch) Ch[row * DP + col] = (__half)v;
            else    C[row * DP + col] = v;
        }
    }
}

// ---------------- batchnorm stats ----------------
__global__ void bn_stats_kernel(const float* __restrict__ h, float* __restrict__ sum,
                                float* __restrict__ sq, int n) {
    int col = threadIdx.x;
    float s = 0.f, q = 0.f;
    for (int row = blockIdx.x; row < n; row += gridDim.x) {
        float v = h[(long)row * DP + col];
        s += v;
        q += v * v;
    }
    atomicAdd(&sum[col], s);
    atomicAdd(&sq[col], q);
}

// ---------------- batchnorm apply -> fp16 h ----------------
__global__ void bn_apply_kernel(const float* __restrict__ h, const float* __restrict__ sum,
                                const float* __restrict__ sq, const float* __restrict__ gamma,
                                const float* __restrict__ beta, __half* __restrict__ outH, int n) {
    long i = (long)blockIdx.x * blockDim.x + threadIdx.x;
    if (i >= (long)n * DP) return;
    int c = (int)(i & 127);
    float v = 0.f;
    if (c < DIM) {
        float inv_n = 1.0f / (float)n;
        float mu = sum[c] * inv_n;
        float var = sq[c] * inv_n - mu * mu;
        float rs = rsqrtf(var + EPSBN);
        v = (h[i] - mu) * rs * gamma[c] + beta[c];
    }
    outH[i] = (__half)v;
}

// ---------------- graph boundaries ----------------
__global__ void gbounds_kernel(const int* __restrict__ batch, int* __restrict__ gstart, int n) {
    int g = threadIdx.x;
    int lo = 0, hi = n;
    while (lo < hi) {
        int mid = (lo + hi) >> 1;
        if (batch[mid] < g) lo = mid + 1; else hi = mid;
    }
    gstart[g] = lo;
    if (g == 0) gstart[NGRAPH] = n;
}

// ---------------- global add pool ----------------
__global__ __launch_bounds__(512) void pool_kernel(const float* __restrict__ a,
                                                   const int* __restrict__ gstart,
                                                   float* __restrict__ g) {
    __shared__ float red[512];
    int b = blockIdx.x, tid = threadIdx.x;
    int col = tid & 127;
    int quarter = tid >> 7;
    int lo = gstart[b], hi = gstart[b + 1];
    float s = 0.f;
    for (int r = lo + quarter; r < hi; r += 4)
        s += a[(long)r * DP + col];
    red[tid] = s;
    __syncthreads();
    if (tid < 128)
        g[b * DP + tid] = red[tid] + red[tid + 128] + red[tid + 256] + red[tid + 384];
}

// ---------------- fused MLP head ----------------
__global__ __launch_bounds__(256) void mlp_kernel(
        const float* __restrict__ g,
        const float* __restrict__ Wf1, const float* __restrict__ bf1,
        const float* __restrict__ Wf2, const float* __restrict__ bf2,
        const float* __restrict__ Wf3, const float* __restrict__ bf3,
        const float* __restrict__ Wf4, const float* __restrict__ bf4,
        float* __restrict__ out) {
    __shared__ float a0[100], a1[200], a2[300], a3[200], red[256];
    int b = blockIdx.x, tid = threadIdx.x;
    if (tid < 100) a0[tid] = g[b * DP + tid];
    __syncthreads();
    for (int c = tid; c < 200; c += 256) {
        float s = bf1[c];
        for (int k = 0; k < 100; k++) s += a0[k] * Wf1[k * 200 + c];
        a1[c] = fmaxf(s, 0.f);
    }
    __syncthreads();
    for (int c = tid; c < 300; c += 256) {
        float s = bf2[c];
        for (int k = 0; k < 200; k++) s += a1[k] * Wf2[k * 300 + c];
        a2[c] = fmaxf(s, 0.f);
    }
    __syncthreads();
    for (int c = tid; c < 200; c += 256) {
        float s = bf3[c];
        for (int k = 0; k < 300; k++) s += a2[k] * Wf3[k * 200 + c];
        a3[c] = fmaxf(s, 0.f);
    }
    __syncthreads();
    red[tid] = (tid < 200) ? a3[tid] * Wf4[tid] : 0.f;
    __syncthreads();
    for (int o = 128; o > 0; o >>= 1) {
        if (tid < o) red[tid] += red[tid + o];
        __syncthreads();
    }
    if (tid == 0) out[b] = red[0] + bf4[0];
}

extern "C" void kernel_launch(void* const* d_in, const int* in_sizes, int n_in,
                              void* d_out, int out_size, void* d_ws, size_t ws_size,
                              hipStream_t stream) {
    const float* x      = (const float*)d_in[0];
    const int*   src    = (const int*)d_in[1];
    const int*   dst    = (const int*)d_in[2];
    const int*   batch  = (const int*)d_in[3];
    const float* W1     = (const float*)d_in[4];
    const float* b1     = (const float*)d_in[5];
    const float* W2     = (const float*)d_in[6];
    const float* b2     = (const float*)d_in[7];
    const float* gamma  = (const float*)d_in[8];
    const float* beta   = (const float*)d_in[9];
    const float* Wa_init= (const float*)d_in[10];
    const float* Wa_root= (const float*)d_in[11];
    const float* ba     = (const float*)d_in[12];
    const float* Wf1    = (const float*)d_in[13];
    const float* bf1    = (const float*)d_in[14];
    const float* Wf2    = (const float*)d_in[15];
    const float* bf2    = (const float*)d_in[16];
    const float* Wf3    = (const float*)d_in[17];
    const float* bf3    = (const float*)d_in[18];
    const float* Wf4    = (const float*)d_in[19];
    const float* bf4    = (const float*)d_in[20];
    float* out = (float*)d_out;

    const int n = NNODES;
    const int e = NEDGES;

    char* ws = (char*)d_ws;
    auto carve = [&](size_t bytes) -> void* {
        void* p = (void*)ws;
        ws += (bytes + 255) & ~(size_t)255;
        return p;
    };
    float*  bufB    = (float*)carve((size_t)n * DP * 4);    // fp32: h2 / final a
    __half* bufH    = (__half*)carve((size_t)n * DP * 2);   // prop input
    __half* bufHA   = (__half*)carve((size_t)n * DP * 2);   // prop output / matmul A / addend
    __half* bufHB   = (__half*)carve((size_t)n * DP * 2);   // BN'd h fp16
    _Float16* Wt1   = (_Float16*)carve((size_t)DP * DP * 2);
    _Float16* Wt2   = (_Float16*)carve((size_t)DP * DP * 2);
    _Float16* Wt3   = (_Float16*)carve((size_t)DP * DP * 2);
    _Float16* Wt4   = (_Float16*)carve((size_t)DP * DP * 2);
    int*    hist    = (int*)carve((size_t)n * 4);
    int*    off     = (int*)carve((size_t)(n + 1) * 4);
    int*    bcursor = (int*)carve((size_t)NBUK * 4);
    int*    partials= (int*)carve(512 * 4);
    int*    ssorted = (int*)carve((size_t)e * 4);
    int2*   gpairs  = (int2*)carve((size_t)e * 8);
    float*  dinv_sl = (float*)carve((size_t)n * 4);
    float*  dinv_nsl= (float*)carve((size_t)n * 4);
    float*  bnsum   = (float*)carve(DP * 4);
    float*  bnsq    = (float*)carve(DP * 4);
    int*    gstart  = (int*)carve((size_t)(NGRAPH + 1) * 4);
    float*  gpool   = (float*)carve((size_t)NGRAPH * DP * 4);

    const int nb = (n + 255) / 256;
    const int wblk = (DP * DP + 255) / 256;

    // ---- pack weights to fp16 transposed (once per launch) ----
    packW_kernel<<<wblk, 256, 0, stream>>>(W1, Wt1, 128, DIM);
    packW_kernel<<<wblk, 256, 0, stream>>>(W2, Wt2, DIM, DIM);
    packW_kernel<<<wblk, 256, 0, stream>>>(Wa_init, Wt3, DIM, DIM);
    packW_kernel<<<wblk, 256, 0, stream>>>(Wa_root, Wt4, DIM, DIM);

    // ---- build CSR by dst (bucketed two-pass scatter) ----
    hipMemsetAsync(hist, 0, (size_t)n * 4, stream);
    hist_kernel<<<(e + 255) / 256, 256, 0, stream>>>(dst, hist, e);
    dinv_kernel<<<(n + 255) / 256, 256, 0, stream>>>(hist, dinv_sl, dinv_nsl, n);
    scan1_kernel<<<nb, 256, 0, stream>>>(hist, off, partials, n);
    scan2_kernel<<<1, 512, 0, stream>>>(partials, nb);
    scan3_kernel<<<nb, 256, 0, stream>>>(off, partials, bcursor, n, e);
    bin_kernel<<<(e + BINCH - 1) / BINCH, 256, 0, stream>>>(src, dst, bcursor, gpairs, e);
    bucket_scatter_kernel<<<NBUK, 256, 0, stream>>>(gpairs, off, ssorted, n);
    gbounds_kernel<<<1, 512, 0, stream>>>(batch, gstart, n);

    const int prop_blocks = (n + 3) / 4;
    const int mm_blocks = (n + 63) / 64;

    // ---- SGConv 1: pre = x*dinv (fp16); prop; h1' = relu(prop@W1+b1)*dinv -> fp16 ----
    prescale_kernel<<<(int)(((long)n * 32 + 255) / 256), 256, 0, stream>>>(x, dinv_sl, bufH, n);
    prop_kernel<<<prop_blocks, 256, 0, stream>>>(bufH, ssorted, off, dinv_sl, bufHA, n, 1);
    matmul_mfma_kernel<<<mm_blocks, 256, 0, stream>>>(bufHA, Wt1, b1, nullptr, dinv_sl, nullptr, bufH, n, DIM, 1);

    // ---- SGConv 2: prop on fp16 h1'; h2 = relu(prop@W2+b2) (fp32 for BN) ----
    prop_kernel<<<prop_blocks, 256, 0, stream>>>(bufH, ssorted, off, dinv_sl, bufHA, n, 1);
    matmul_mfma_kernel<<<mm_blocks, 256, 0, stream>>>(bufHA, Wt2, b2, nullptr, nullptr, bufB, nullptr, n, DIM, 1);

    // ---- BatchNorm -> fp16 h ----
    hipMemsetAsync(bnsum, 0, DP * 4, stream);
    hipMemsetAsync(bnsq, 0, DP * 4, stream);
    bn_stats_kernel<<<512, 128, 0, stream>>>(bufB, bnsum, bnsq, n);
    bn_apply_kernel<<<(int)(((long)n * DP + 255) / 256), 256, 0, stream>>>(bufB, bnsum, bnsq, gamma, beta, bufHB, n);

    // ---- ARMAConv: t = (h@Wa_init)*dinv_nsl (fp16); prop(no SL); relu(h@Wa_root+ba+t_prop) ----
    matmul_mfma_kernel<<<mm_blocks, 256, 0, stream>>>(bufHB, Wt3, nullptr, nullptr, dinv_nsl, nullptr, bufH, n, DIM, 0);
    prop_kernel<<<prop_blocks, 256, 0, stream>>>(bufH, ssorted, off, dinv_nsl, bufHA, n, 0);
    matmul_mfma_kernel<<<mm_blocks, 256, 0, stream>>>(bufHB, Wt4, ba, bufHA, nullptr, bufB, nullptr, n, DIM, 1);

    // ---- global add pool ----
    pool_kernel<<<NGRAPH, 512, 0, stream>>>(bufB, gstart, gpool);

    // ---- MLP head ----
    mlp_kernel<<<NGRAPH, 256, 0, stream>>>(gpool, Wf1, bf1, Wf2, bf2, Wf3, bf3, Wf4, bf4, out);
}

// Round 9
// 701.823 us; speedup vs baseline: 1.2066x; 1.1473x over previous
//
#include <hip/hip_runtime.h>
#include <hip/hip_fp16.h>

#define NNODES 100000
#define NEDGES 1600000
#define NGRAPH 512
#define DIM    100
#define DP     128
#define EPSBN  1e-5f
#define NBUK   ((NNODES + 255) >> 8)   // 391 dst-buckets of 256 nodes
#define BINCH  8192                    // edges per bin block

typedef _Float16 half8 __attribute__((ext_vector_type(8)));
typedef float floatx4 __attribute__((ext_vector_type(4)));

// ---------------- pass 0: per-chunk bucket counts (LDS), accumulate to global ----------------
__global__ __launch_bounds__(256) void bin_count_kernel(const int* __restrict__ dst,
                                                        int* __restrict__ btotal, int e) {
    __shared__ int lc[NBUK];
    int tid = threadIdx.x;
    int base = blockIdx.x * BINCH;
    int m = e - base; if (m > BINCH) m = BINCH;
    for (int b = tid; b < NBUK; b += 256) lc[b] = 0;
    __syncthreads();
    for (int j = tid; j < m; j += 256)
        atomicAdd(&lc[dst[base + j] >> 8], 1);
    __syncthreads();
    for (int b = tid; b < NBUK; b += 256)
        if (lc[b]) atomicAdd(&btotal[b], lc[b]);
}

// ---------------- bucket exclusive scan -> bases + cursors ----------------
__global__ void bucket_scan_kernel(const int* __restrict__ btotal, int* __restrict__ bbase,
                                   int* __restrict__ bcursor, int e) {
    __shared__ int s[512];
    int tid = threadIdx.x;
    int v = (tid < NBUK) ? btotal[tid] : 0;
    s[tid] = v; __syncthreads();
    for (int o = 1; o < 512; o <<= 1) {
        int t = (tid >= o) ? s[tid - o] : 0;
        __syncthreads();
        s[tid] += t;
        __syncthreads();
    }
    if (tid < NBUK) {
        int base = s[tid] - v;
        bbase[tid] = base;
        bcursor[tid] = base;
    }
    if (tid == 0) bbase[NBUK] = e;
}

// ---------------- pass 1: bin (src,dst) pairs bucket-major with LDS staging ----------------
__global__ __launch_bounds__(256) void bin_kernel(
        const int* __restrict__ src, const int* __restrict__ dst,
        int* __restrict__ bcursor, int2* __restrict__ gpairs, int e) {
    __shared__ int2 lpairs[BINCH];
    __shared__ int lcount[NBUK], lstart[NBUK], lcur[NBUK], gbase[NBUK];
    int tid = threadIdx.x;
    int base = blockIdx.x * BINCH;
    int m = e - base; if (m > BINCH) m = BINCH;

    for (int b = tid; b < NBUK; b += 256) lcount[b] = 0;
    __syncthreads();

    for (int j = tid; j < m; j += 256)
        atomicAdd(&lcount[dst[base + j] >> 8], 1);
    __syncthreads();

    if (tid == 0) {
        int acc = 0;
        for (int b = 0; b < NBUK; b++) {
            lstart[b] = acc;
            lcur[b] = acc;
            acc += lcount[b];
        }
    }
    __syncthreads();

    for (int b = tid; b < NBUK; b += 256)
        gbase[b] = atomicAdd(&bcursor[b], lcount[b]);
    for (int j = tid; j < m; j += 256) {
        int s = src[base + j], d = dst[base + j];
        int p = atomicAdd(&lcur[d >> 8], 1);
        lpairs[p] = make_int2(s, d);
    }
    __syncthreads();

    for (int j = tid; j < m; j += 256) {
        int2 pr = lpairs[j];
        int b = pr.y >> 8;
        gpairs[gbase[b] + (j - lstart[b])] = pr;
    }
}

// ---------------- pass 2: per-bucket degree count + scan + dinv + scatter (fused) ----------------
__global__ __launch_bounds__(256) void bucket_build_kernel(
        const int2* __restrict__ gpairs, const int* __restrict__ bbase,
        int* __restrict__ off, int* __restrict__ ssorted,
        float* __restrict__ dsl, float* __restrict__ dnsl, int n, int e) {
    __shared__ int cnt[256];
    __shared__ int sc[256];
    int b = blockIdx.x, tid = threadIdx.x;
    int node0 = b << 8;
    int e0 = bbase[b], e1 = bbase[b + 1];

    cnt[tid] = 0;
    __syncthreads();
    for (int j = e0 + tid; j < e1; j += 256)
        atomicAdd(&cnt[gpairs[j].y & 255], 1);
    __syncthreads();

    int c = cnt[tid];
    sc[tid] = c; __syncthreads();
    for (int o = 1; o < 256; o <<= 1) {
        int t = (tid >= o) ? sc[tid - o] : 0;
        __syncthreads();
        sc[tid] += t;
        __syncthreads();
    }
    int excl = sc[tid] - c;

    int node = node0 + tid;
    if (node < n) {
        off[node] = e0 + excl;
        float cf = (float)c;
        dsl[node] = rsqrtf(cf + 1.0f);
        dnsl[node] = (c > 0) ? rsqrtf(cf) : 0.0f;
    }
    if (b == NBUK - 1 && tid == 0) off[n] = e;

    __syncthreads();
    cnt[tid] = e0 + excl;   // per-node write cursor
    __syncthreads();
    for (int j = e0 + tid; j < e1; j += 256) {
        int2 pr = gpairs[j];
        int p = atomicAdd(&cnt[pr.y & 255], 1);
        ssorted[p] = pr.x;
    }
}

// ---------------- prescale rows to fp16 ----------------
__global__ void prescale_kernel(const float* __restrict__ x, const float* __restrict__ d,
                                __half* __restrict__ yh, int n) {
    long i = (long)blockIdx.x * blockDim.x + threadIdx.x;
    if (i >= (long)n * 32) return;
    int row = (int)(i >> 5);
    float s = d[row];
    float4 v = ((const float4*)x)[i];
    __half2 p01 = __floats2half2_rn(v.x * s, v.y * s);
    __half2 p23 = __floats2half2_rn(v.z * s, v.w * s);
    uint2 u;
    u.x = *(unsigned int*)&p01;
    u.y = *(unsigned int*)&p23;
    ((uint2*)yh)[i] = u;
}

// ---------------- pack W: fp32 [K,Kout] -> fp16 transposed [128,128] ----------------
__global__ void packW_kernel(const float* __restrict__ W, _Float16* __restrict__ Wt,
                             int K, int Kout) {
    int idx = blockIdx.x * 256 + threadIdx.x;
    if (idx >= DP * DP) return;
    int nn = idx >> 7, k = idx & 127;
    float v = (k < K && nn < Kout) ? W[k * Kout + nn] : 0.f;
    Wt[nn * DP + k] = (_Float16)v;
}

// ---------------- propagation: one wave per node, fp16 rows, fp32 acc, fp16 out ----------------
__global__ __launch_bounds__(256) void prop_kernel(
        const __half* __restrict__ pre, const int* __restrict__ ssorted,
        const int* __restrict__ off, const float* __restrict__ dinv,
        __half* __restrict__ outH, int n, int selfloop) {
    int wave = (blockIdx.x * blockDim.x + threadIdx.x) >> 6;
    int lane = threadIdx.x & 63;
    if (wave >= n) return;
    int e0 = off[wave], e1 = off[wave + 1];
    int deg = e1 - e0;
    int half_id = lane >> 5;
    int l32  = lane & 31;
    int c0 = l32 * 4;

    float4 acc = make_float4(0.f, 0.f, 0.f, 0.f);

    auto addrow = [&](int s, float4& a) {
        uint2 u = *(const uint2*)&pre[(long)s * DP + c0];
        __half2 h01 = *(__half2*)&u.x;
        __half2 h23 = *(__half2*)&u.y;
        float2 f01 = __half22float2(h01);
        float2 f23 = __half22float2(h23);
        a.x += f01.x; a.y += f01.y; a.z += f23.x; a.w += f23.y;
    };

    for (int base = 0; base < deg; base += 64) {
        int m = deg - base; if (m > 64) m = 64;
        int sidx = (lane < m) ? ssorted[e0 + base + lane] : 0;
        int j = 0;
        for (; j + 8 <= m; j += 8) {
            int sA = __shfl(sidx, j + half_id);
            int sB = __shfl(sidx, j + 2 + half_id);
            int sC = __shfl(sidx, j + 4 + half_id);
            int sD = __shfl(sidx, j + 6 + half_id);
            uint2 uA = *(const uint2*)&pre[(long)sA * DP + c0];
            uint2 uB = *(const uint2*)&pre[(long)sB * DP + c0];
            uint2 uC = *(const uint2*)&pre[(long)sC * DP + c0];
            uint2 uD = *(const uint2*)&pre[(long)sD * DP + c0];
            float2 a0 = __half22float2(*(__half2*)&uA.x), a1 = __half22float2(*(__half2*)&uA.y);
            float2 b0 = __half22float2(*(__half2*)&uB.x), b1 = __half22float2(*(__half2*)&uB.y);
            float2 c0f = __half22float2(*(__half2*)&uC.x), c1 = __half22float2(*(__half2*)&uC.y);
            float2 d0 = __half22float2(*(__half2*)&uD.x), d1 = __half22float2(*(__half2*)&uD.y);
            acc.x += (a0.x + b0.x) + (c0f.x + d0.x);
            acc.y += (a0.y + b0.y) + (c0f.y + d0.y);
            acc.z += (a1.x + b1.x) + (c1.x + d1.x);
            acc.w += (a1.y + b1.y) + (c1.y + d1.y);
        }
        for (; j + 2 <= m; j += 2) {
            int s = __shfl(sidx, j + half_id);
            addrow(s, acc);
        }
        if (j < m) {
            int s = __shfl(sidx, j);
            if (half_id == 0) addrow(s, acc);
        }
    }

    acc.x += __shfl(acc.x, l32 + 32);
    acc.y += __shfl(acc.y, l32 + 32);
    acc.z += __shfl(acc.z, l32 + 32);
    acc.w += __shfl(acc.w, l32 + 32);

    if (half_id == 0) {
        float dn = dinv[wave];
        if (selfloop) addrow(wave, acc);
        __half2 p01 = __floats2half2_rn(dn * acc.x, dn * acc.y);
        __half2 p23 = __floats2half2_rn(dn * acc.z, dn * acc.w);
        uint2 u;
        u.x = *(unsigned int*)&p01;
        u.y = *(unsigned int*)&p23;
        *(uint2*)&outH[(long)wave * DP + c0] = u;
    }
}

// ---------------- MFMA matmul, B from prepacked global Wt; LDS-staged coalesced epilogue ----------------
__global__ __launch_bounds__(256) void matmul_mfma_kernel(
        const __half* __restrict__ A, const _Float16* __restrict__ Wt,
        const float* __restrict__ bias, const __half* __restrict__ addendH,
        const float* __restrict__ rowscale,
        float* __restrict__ C, __half* __restrict__ Ch,
        int M, int Kout, int relu) {
    __shared__ float Ct[64 * 132];     // 64 rows x 128 cols, stride 132 (33.8 KB)
    int tid = threadIdx.x;
    int wave = tid >> 6;
    int lane = tid & 63;
    int m16 = lane & 15;
    int quad = lane >> 4;
    long row0blk = (long)blockIdx.x * 64;
    long row0 = row0blk + wave * 16;

    half8 af[4];
    {
        long ar = row0 + m16; if (ar >= M) ar = M - 1;
        const _Float16* Ap = (const _Float16*)&A[ar * DP + quad * 8];
#pragma unroll
        for (int k0 = 0; k0 < 4; k0++)
            af[k0] = *(const half8*)(Ap + k0 * 32);
    }

    floatx4 acc[8];
#pragma unroll
    for (int t = 0; t < 8; t++) acc[t] = (floatx4){0.f, 0.f, 0.f, 0.f};

#pragma unroll
    for (int t = 0; t < 8; t++) {
        const _Float16* Wp = &Wt[(t * 16 + m16) * DP + quad * 8];
#pragma unroll
        for (int k0 = 0; k0 < 4; k0++) {
            half8 bf = *(const half8*)(Wp + k0 * 32);
            acc[t] = __builtin_amdgcn_mfma_f32_16x16x32_f16(af[k0], bf, acc[t], 0, 0, 0);
        }
    }

    // stage to LDS (2-way banks at worst)
    int lrow0 = wave * 16 + quad * 4;
#pragma unroll
    for (int t = 0; t < 8; t++) {
#pragma unroll
        for (int r = 0; r < 4; r++)
            Ct[(lrow0 + r) * 132 + t * 16 + m16] = acc[t][r];
    }
    __syncthreads();

    // cooperative coalesced epilogue: 64 rows x 32 float4
    for (int idx = tid; idx < 64 * 32; idx += 256) {
        int lr = idx >> 5, c4 = idx & 31;
        long grow = row0blk + lr;
        if (grow >= M) continue;
        int col = c4 * 4;
        float4 v = *(const float4*)&Ct[lr * 132 + col];
        if (bias && col < Kout) {
            float4 bb = *(const float4*)&bias[col];
            v.x += bb.x; v.y += bb.y; v.z += bb.z; v.w += bb.w;
        }
        if (addendH) {
            uint2 u = *(const uint2*)&addendH[grow * DP + col];
            float2 f01 = __half22float2(*(__half2*)&u.x);
            float2 f23 = __half22float2(*(__half2*)&u.y);
            v.x += f01.x; v.y += f01.y; v.z += f23.x; v.w += f23.y;
        }
        if (relu) {
            v.x = fmaxf(v.x, 0.f); v.y = fmaxf(v.y, 0.f);
            v.z = fmaxf(v.z, 0.f); v.w = fmaxf(v.w, 0.f);
        }
        if (rowscale) {
            float rs = rowscale[grow];
            v.x *= rs; v.y *= rs; v.z *= rs; v.w *= rs;
        }
        if (Ch) {
            __half2 p01 = __floats2half2_rn(v.x, v.y);
            __half2 p23 = __floats2half2_rn(v.z, v.w);
            uint2 u;
            u.x = *(unsigned int*)&p01;
            u.y = *(unsigned int*)&p23;
            *(uint2*)&Ch[grow * DP + col] = u;
        } else {
            *(float4*)&C[grow * DP + col] = v;
        }
    }
}

// ---------------- batchnorm stats ----------------
__global__ void bn_stats_kernel(const float* __restrict__ h, float* __restrict__ sum,
                                float* __restrict__ sq, int n) {
    int col = threadIdx.x;
    float s = 0.f, q = 0.f;
    for (int row = blockIdx.x; row < n; row += gridDim.x) {
        float v = h[(long)row * DP + col];
        s += v;
        q += v * v;
    }
    atomicAdd(&sum[col], s);
    atomicAdd(&sq[col], q);
}

// ---------------- batchnorm apply -> fp16 h ----------------
__global__ void bn_apply_kernel(const float* __restrict__ h, const float* __restrict__ sum,
                                const float* __restrict__ sq, const float* __restrict__ gamma,
                                const float* __restrict__ beta, __half* __restrict__ outH, int n) {
    long i = (long)blockIdx.x * blockDim.x + threadIdx.x;
    if (i >= (long)n * DP) return;
    int c = (int)(i & 127);
    float v = 0.f;
    if (c < DIM) {
        float inv_n = 1.0f / (float)n;
        float mu = sum[c] * inv_n;
        float var = sq[c] * inv_n - mu * mu;
        float rs = rsqrtf(var + EPSBN);
        v = (h[i] - mu) * rs * gamma[c] + beta[c];
    }
    outH[i] = (__half)v;
}

// ---------------- graph boundaries ----------------
__global__ void gbounds_kernel(const int* __restrict__ batch, int* __restrict__ gstart, int n) {
    int g = threadIdx.x;
    int lo = 0, hi = n;
    while (lo < hi) {
        int mid = (lo + hi) >> 1;
        if (batch[mid] < g) lo = mid + 1; else hi = mid;
    }
    gstart[g] = lo;
    if (g == 0) gstart[NGRAPH] = n;
}

// ---------------- global add pool ----------------
__global__ __launch_bounds__(512) void pool_kernel(const float* __restrict__ a,
                                                   const int* __restrict__ gstart,
                                                   float* __restrict__ g) {
    __shared__ float red[512];
    int b = blockIdx.x, tid = threadIdx.x;
    int col = tid & 127;
    int quarter = tid >> 7;
    int lo = gstart[b], hi = gstart[b + 1];
    float s = 0.f;
    for (int r = lo + quarter; r < hi; r += 4)
        s += a[(long)r * DP + col];
    red[tid] = s;
    __syncthreads();
    if (tid < 128)
        g[b * DP + tid] = red[tid] + red[tid + 128] + red[tid + 256] + red[tid + 384];
}

// ---------------- fused MLP head ----------------
__global__ __launch_bounds__(256) void mlp_kernel(
        const float* __restrict__ g,
        const float* __restrict__ Wf1, const float* __restrict__ bf1,
        const float* __restrict__ Wf2, const float* __restrict__ bf2,
        const float* __restrict__ Wf3, const float* __restrict__ bf3,
        const float* __restrict__ Wf4, const float* __restrict__ bf4,
        float* __restrict__ out) {
    __shared__ float a0[100], a1[200], a2[300], a3[200], red[256];
    int b = blockIdx.x, tid = threadIdx.x;
    if (tid < 100) a0[tid] = g[b * DP + tid];
    __syncthreads();
    for (int c = tid; c < 200; c += 256) {
        float s = bf1[c];
        for (int k = 0; k < 100; k++) s += a0[k] * Wf1[k * 200 + c];
        a1[c] = fmaxf(s, 0.f);
    }
    __syncthreads();
    for (int c = tid; c < 300; c += 256) {
        float s = bf2[c];
        for (int k = 0; k < 200; k++) s += a1[k] * Wf2[k * 300 + c];
        a2[c] = fmaxf(s, 0.f);
    }
    __syncthreads();
    for (int c = tid; c < 200; c += 256) {
        float s = bf3[c];
        for (int k = 0; k < 300; k++) s += a2[k] * Wf3[k * 200 + c];
        a3[c] = fmaxf(s, 0.f);
    }
    __syncthreads();
    red[tid] = (tid < 200) ? a3[tid] * Wf4[tid] : 0.f;
    __syncthreads();
    for (int o = 128; o > 0; o >>= 1) {
        if (tid < o) red[tid] += red[tid + o];
        __syncthreads();
    }
    if (tid == 0) out[b] = red[0] + bf4[0];
}

extern "C" void kernel_launch(void* const* d_in, const int* in_sizes, int n_in,
                              void* d_out, int out_size, void* d_ws, size_t ws_size,
                              hipStream_t stream) {
    const float* x      = (const float*)d_in[0];
    const int*   src    = (const int*)d_in[1];
    const int*   dst    = (const int*)d_in[2];
    const int*   batch  = (const int*)d_in[3];
    const float* W1     = (const float*)d_in[4];
    const float* b1     = (const float*)d_in[5];
    const float* W2     = (const float*)d_in[6];
    const float* b2     = (const float*)d_in[7];
    const float* gamma  = (const float*)d_in[8];
    const float* beta   = (const float*)d_in[9];
    const float* Wa_init= (const float*)d_in[10];
    const float* Wa_root= (const float*)d_in[11];
    const float* ba     = (const float*)d_in[12];
    const float* Wf1    = (const float*)d_in[13];
    const float* bf1    = (const float*)d_in[14];
    const float* Wf2    = (const float*)d_in[15];
    const float* bf2    = (const float*)d_in[16];
    const float* Wf3    = (const float*)d_in[17];
    const float* bf3    = (const float*)d_in[18];
    const float* Wf4    = (const float*)d_in[19];
    const float* bf4    = (const float*)d_in[20];
    float* out = (float*)d_out;

    const int n = NNODES;
    const int e = NEDGES;

    char* ws = (char*)d_ws;
    auto carve = [&](size_t bytes) -> void* {
        void* p = (void*)ws;
        ws += (bytes + 255) & ~(size_t)255;
        return p;
    };
    float*  bufB    = (float*)carve((size_t)n * DP * 4);    // fp32: h2 / final a
    __half* bufH    = (__half*)carve((size_t)n * DP * 2);   // prop input
    __half* bufHA   = (__half*)carve((size_t)n * DP * 2);   // prop output / matmul A / addend
    __half* bufHB   = (__half*)carve((size_t)n * DP * 2);   // BN'd h fp16
    _Float16* Wt1   = (_Float16*)carve((size_t)DP * DP * 2);
    _Float16* Wt2   = (_Float16*)carve((size_t)DP * DP * 2);
    _Float16* Wt3   = (_Float16*)carve((size_t)DP * DP * 2);
    _Float16* Wt4   = (_Float16*)carve((size_t)DP * DP * 2);
    int*    off     = (int*)carve((size_t)(n + 1) * 4);
    int*    btotal  = (int*)carve((size_t)NBUK * 4);
    int*    bbase   = (int*)carve((size_t)(NBUK + 1) * 4);
    int*    bcursor = (int*)carve((size_t)NBUK * 4);
    int*    ssorted = (int*)carve((size_t)e * 4);
    int2*   gpairs  = (int2*)carve((size_t)e * 8);
    float*  dinv_sl = (float*)carve((size_t)n * 4);
    float*  dinv_nsl= (float*)carve((size_t)n * 4);
    float*  bnsum   = (float*)carve(DP * 4);
    float*  bnsq    = (float*)carve(DP * 4);
    int*    gstart  = (int*)carve((size_t)(NGRAPH + 1) * 4);
    float*  gpool   = (float*)carve((size_t)NGRAPH * DP * 4);

    const int wblk = (DP * DP + 255) / 256;
    const int nchunk = (e + BINCH - 1) / BINCH;

    // ---- pack weights to fp16 transposed ----
    packW_kernel<<<wblk, 256, 0, stream>>>(W1, Wt1, 128, DIM);
    packW_kernel<<<wblk, 256, 0, stream>>>(W2, Wt2, DIM, DIM);
    packW_kernel<<<wblk, 256, 0, stream>>>(Wa_init, Wt3, DIM, DIM);
    packW_kernel<<<wblk, 256, 0, stream>>>(Wa_root, Wt4, DIM, DIM);

    // ---- build CSR by dst: bucket counts -> scan -> bin -> fused build ----
    hipMemsetAsync(btotal, 0, (size_t)NBUK * 4, stream);
    bin_count_kernel<<<nchunk, 256, 0, stream>>>(dst, btotal, e);
    bucket_scan_kernel<<<1, 512, 0, stream>>>(btotal, bbase, bcursor, e);
    bin_kernel<<<nchunk, 256, 0, stream>>>(src, dst, bcursor, gpairs, e);
    bucket_build_kernel<<<NBUK, 256, 0, stream>>>(gpairs, bbase, off, ssorted, dinv_sl, dinv_nsl, n, e);
    gbounds_kernel<<<1, 512, 0, stream>>>(batch, gstart, n);

    const int prop_blocks = (n + 3) / 4;
    const int mm_blocks = (n + 63) / 64;

    // ---- SGConv 1: pre = x*dinv (fp16); prop; h1' = relu(prop@W1+b1)*dinv -> fp16 ----
    prescale_kernel<<<(int)(((long)n * 32 + 255) / 256), 256, 0, stream>>>(x, dinv_sl, bufH, n);
    prop_kernel<<<prop_blocks, 256, 0, stream>>>(bufH, ssorted, off, dinv_sl, bufHA, n, 1);
    matmul_mfma_kernel<<<mm_blocks, 256, 0, stream>>>(bufHA, Wt1, b1, nullptr, dinv_sl, nullptr, bufH, n, DIM, 1);

    // ---- SGConv 2: prop on fp16 h1'; h2 = relu(prop@W2+b2) (fp32 for BN) ----
    prop_kernel<<<prop_blocks, 256, 0, stream>>>(bufH, ssorted, off, dinv_sl, bufHA, n, 1);
    matmul_mfma_kernel<<<mm_blocks, 256, 0, stream>>>(bufHA, Wt2, b2, nullptr, nullptr, bufB, nullptr, n, DIM, 1);

    // ---- BatchNorm -> fp16 h ----
    hipMemsetAsync(bnsum, 0, DP * 4, stream);
    hipMemsetAsync(bnsq, 0, DP * 4, stream);
    bn_stats_kernel<<<512, 128, 0, stream>>>(bufB, bnsum, bnsq, n);
    bn_apply_kernel<<<(int)(((long)n * DP + 255) / 256), 256, 0, stream>>>(bufB, bnsum, bnsq, gamma, beta, bufHB, n);

    // ---- ARMAConv: t = (h@Wa_init)*dinv_nsl (fp16); prop(no SL); relu(h@Wa_root+ba+t_prop) ----
    matmul_mfma_kernel<<<mm_blocks, 256, 0, stream>>>(bufHB, Wt3, nullptr, nullptr, dinv_nsl, nullptr, bufH, n, DIM, 0);
    prop_kernel<<<prop_blocks, 256, 0, stream>>>(bufH, ssorted, off, dinv_nsl, bufHA, n, 0);
    matmul_mfma_kernel<<<mm_blocks, 256, 0, stream>>>(bufHB, Wt4, ba, bufHA, nullptr, bufB, nullptr, n, DIM, 1);

    // ---- global add pool ----
    pool_kernel<<<NGRAPH, 512, 0, stream>>>(bufB, gstart, gpool);

    // ---- MLP head ----
    mlp_kernel<<<NGRAPH, 256, 0, stream>>>(gpool, Wf1, bf1, Wf2, bf2, Wf3, bf3, Wf4, bf4, out);
}

// Round 10
// 692.796 us; speedup vs baseline: 1.2223x; 1.0130x over previous
//
#include <hip/hip_runtime.h>
#include <hip/hip_fp16.h>

#define NNODES 100000
#define NEDGES 1600000
#define NGRAPH 512
#define DIM    100
#define DP     128
#define EPSBN  1e-5f
#define NBUK   ((NNODES + 255) >> 8)   // 391 dst-buckets of 256 nodes
#define BINCH  8192                    // edges per bin block

typedef _Float16 half8 __attribute__((ext_vector_type(8)));
typedef float floatx4 __attribute__((ext_vector_type(4)));

// ---------------- pass 0: per-chunk bucket counts (LDS), accumulate to global ----------------
__global__ __launch_bounds__(256) void bin_count_kernel(const int* __restrict__ dst,
                                                        int* __restrict__ btotal, int e) {
    __shared__ int lc[NBUK];
    int tid = threadIdx.x;
    int base = blockIdx.x * BINCH;
    int m = e - base; if (m > BINCH) m = BINCH;
    for (int b = tid; b < NBUK; b += 256) lc[b] = 0;
    __syncthreads();
    for (int j = tid; j < m; j += 256)
        atomicAdd(&lc[dst[base + j] >> 8], 1);
    __syncthreads();
    for (int b = tid; b < NBUK; b += 256)
        if (lc[b]) atomicAdd(&btotal[b], lc[b]);
}

// ---------------- bucket exclusive scan -> bases + cursors ----------------
__global__ void bucket_scan_kernel(const int* __restrict__ btotal, int* __restrict__ bbase,
                                   int* __restrict__ bcursor, int e) {
    __shared__ int s[512];
    int tid = threadIdx.x;
    int v = (tid < NBUK) ? btotal[tid] : 0;
    s[tid] = v; __syncthreads();
    for (int o = 1; o < 512; o <<= 1) {
        int t = (tid >= o) ? s[tid - o] : 0;
        __syncthreads();
        s[tid] += t;
        __syncthreads();
    }
    if (tid < NBUK) {
        int base = s[tid] - v;
        bbase[tid] = base;
        bcursor[tid] = base;
    }
    if (tid == 0) bbase[NBUK] = e;
}

// ---------------- pass 1: bin (src,dst) pairs bucket-major with LDS staging ----------------
__global__ __launch_bounds__(256) void bin_kernel(
        const int* __restrict__ src, const int* __restrict__ dst,
        int* __restrict__ bcursor, int2* __restrict__ gpairs, int e) {
    __shared__ int2 lpairs[BINCH];
    __shared__ int lcount[NBUK], lstart[NBUK], lcur[NBUK], gbase[NBUK];
    int tid = threadIdx.x;
    int base = blockIdx.x * BINCH;
    int m = e - base; if (m > BINCH) m = BINCH;

    for (int b = tid; b < NBUK; b += 256) lcount[b] = 0;
    __syncthreads();

    for (int j = tid; j < m; j += 256)
        atomicAdd(&lcount[dst[base + j] >> 8], 1);
    __syncthreads();

    if (tid == 0) {
        int acc = 0;
        for (int b = 0; b < NBUK; b++) {
            lstart[b] = acc;
            lcur[b] = acc;
            acc += lcount[b];
        }
    }
    __syncthreads();

    for (int b = tid; b < NBUK; b += 256)
        gbase[b] = atomicAdd(&bcursor[b], lcount[b]);
    for (int j = tid; j < m; j += 256) {
        int s = src[base + j], d = dst[base + j];
        int p = atomicAdd(&lcur[d >> 8], 1);
        lpairs[p] = make_int2(s, d);
    }
    __syncthreads();

    for (int j = tid; j < m; j += 256) {
        int2 pr = lpairs[j];
        int b = pr.y >> 8;
        gpairs[gbase[b] + (j - lstart[b])] = pr;
    }
}

// ---------------- pass 2: per-bucket degree count + scan + dinv + scatter (fused) ----------------
__global__ __launch_bounds__(256) void bucket_build_kernel(
        const int2* __restrict__ gpairs, const int* __restrict__ bbase,
        int* __restrict__ off, int* __restrict__ ssorted,
        float* __restrict__ dsl, float* __restrict__ dnsl, int n, int e) {
    __shared__ int cnt[256];
    __shared__ int sc[256];
    int b = blockIdx.x, tid = threadIdx.x;
    int node0 = b << 8;
    int e0 = bbase[b], e1 = bbase[b + 1];

    cnt[tid] = 0;
    __syncthreads();
    for (int j = e0 + tid; j < e1; j += 256)
        atomicAdd(&cnt[gpairs[j].y & 255], 1);
    __syncthreads();

    int c = cnt[tid];
    sc[tid] = c; __syncthreads();
    for (int o = 1; o < 256; o <<= 1) {
        int t = (tid >= o) ? sc[tid - o] : 0;
        __syncthreads();
        sc[tid] += t;
        __syncthreads();
    }
    int excl = sc[tid] - c;

    int node = node0 + tid;
    if (node < n) {
        off[node] = e0 + excl;
        float cf = (float)c;
        dsl[node] = rsqrtf(cf + 1.0f);
        dnsl[node] = (c > 0) ? rsqrtf(cf) : 0.0f;
    }
    if (b == NBUK - 1 && tid == 0) off[n] = e;

    __syncthreads();
    cnt[tid] = e0 + excl;   // per-node write cursor
    __syncthreads();
    for (int j = e0 + tid; j < e1; j += 256) {
        int2 pr = gpairs[j];
        int p = atomicAdd(&cnt[pr.y & 255], 1);
        ssorted[p] = pr.x;
    }
}

// ---------------- prescale rows to fp16 ----------------
__global__ void prescale_kernel(const float* __restrict__ x, const float* __restrict__ d,
                                __half* __restrict__ yh, int n) {
    long i = (long)blockIdx.x * blockDim.x + threadIdx.x;
    if (i >= (long)n * 32) return;
    int row = (int)(i >> 5);
    float s = d[row];
    float4 v = ((const float4*)x)[i];
    __half2 p01 = __floats2half2_rn(v.x * s, v.y * s);
    __half2 p23 = __floats2half2_rn(v.z * s, v.w * s);
    uint2 u;
    u.x = *(unsigned int*)&p01;
    u.y = *(unsigned int*)&p23;
    ((uint2*)yh)[i] = u;
}

// ---------------- pack W: fp32 [K,Kout] -> fp16 transposed [128,128] ----------------
__global__ void packW_kernel(const float* __restrict__ W, _Float16* __restrict__ Wt,
                             int K, int Kout) {
    int idx = blockIdx.x * 256 + threadIdx.x;
    if (idx >= DP * DP) return;
    int nn = idx >> 7, k = idx & 127;
    float v = (k < K && nn < Kout) ? W[k * Kout + nn] : 0.f;
    Wt[nn * DP + k] = (_Float16)v;
}

// ---------------- propagation: one wave per node; 16 lanes x 16B per row, 4 edges concurrent ----------------
__global__ __launch_bounds__(256) void prop_kernel(
        const __half* __restrict__ pre, const int* __restrict__ ssorted,
        const int* __restrict__ off, const float* __restrict__ dinv,
        __half* __restrict__ outH, int n, int selfloop) {
    int wave = (blockIdx.x * blockDim.x + threadIdx.x) >> 6;
    int lane = threadIdx.x & 63;
    if (wave >= n) return;
    int e0 = off[wave], e1 = off[wave + 1];
    int deg = e1 - e0;
    int g = lane >> 4;       // edge-group 0..3
    int q = lane & 15;       // 16 lanes x 8 halves = 128 cols

    float acc[8];
#pragma unroll
    for (int i = 0; i < 8; i++) acc[i] = 0.f;

    auto addu = [&](uint4 u) {
        float2 f;
        f = __half22float2(*(__half2*)&u.x); acc[0] += f.x; acc[1] += f.y;
        f = __half22float2(*(__half2*)&u.y); acc[2] += f.x; acc[3] += f.y;
        f = __half22float2(*(__half2*)&u.z); acc[4] += f.x; acc[5] += f.y;
        f = __half22float2(*(__half2*)&u.w); acc[6] += f.x; acc[7] += f.y;
    };
    auto rowptr = [&](int s) -> const uint4* {
        return (const uint4*)&pre[(long)s * DP + q * 8];
    };

    for (int base = 0; base < deg; base += 64) {
        int m = deg - base; if (m > 64) m = 64;
        int sidx = (lane < m) ? ssorted[e0 + base + lane] : 0;
        int j = 0;
        for (; j + 16 <= m; j += 16) {     // 16 edges, 4 dwordx4 loads in flight per lane
            int s0 = __shfl(sidx, j + g);
            int s1 = __shfl(sidx, j + 4 + g);
            int s2 = __shfl(sidx, j + 8 + g);
            int s3 = __shfl(sidx, j + 12 + g);
            uint4 u0 = *rowptr(s0);
            uint4 u1 = *rowptr(s1);
            uint4 u2 = *rowptr(s2);
            uint4 u3 = *rowptr(s3);
            addu(u0); addu(u1); addu(u2); addu(u3);
        }
        for (; j + 4 <= m; j += 4) {       // 4 edges
            int s = __shfl(sidx, j + g);
            addu(*rowptr(s));
        }
        if (j < m) {                       // 1..3 edges: clamp shfl, mask add
            int r = m - j;
            int s = __shfl(sidx, (g < r) ? j + g : j);
            if (g < r) addu(*rowptr(s));
        }
    }

    // combine 4 edge-groups: butterfly over lane bits 4,5
#pragma unroll
    for (int i = 0; i < 8; i++) {
        acc[i] += __shfl_xor(acc[i], 16);
        acc[i] += __shfl_xor(acc[i], 32);
    }

    if (g == 0) {
        float dn = dinv[wave];
        if (selfloop) addu(*rowptr(wave));
        __half2 p0 = __floats2half2_rn(dn * acc[0], dn * acc[1]);
        __half2 p1 = __floats2half2_rn(dn * acc[2], dn * acc[3]);
        __half2 p2 = __floats2half2_rn(dn * acc[4], dn * acc[5]);
        __half2 p3 = __floats2half2_rn(dn * acc[6], dn * acc[7]);
        uint4 u;
        u.x = *(unsigned int*)&p0;
        u.y = *(unsigned int*)&p1;
        u.z = *(unsigned int*)&p2;
        u.w = *(unsigned int*)&p3;
        *(uint4*)&outH[(long)wave * DP + q * 8] = u;
    }
}

// ---------------- MFMA matmul, B from prepacked global Wt; LDS-staged coalesced epilogue ----------------
__global__ __launch_bounds__(256) void matmul_mfma_kernel(
        const __half* __restrict__ A, const _Float16* __restrict__ Wt,
        const float* __restrict__ bias, const __half* __restrict__ addendH,
        const float* __restrict__ rowscale,
        float* __restrict__ C, __half* __restrict__ Ch,
        int M, int Kout, int relu) {
    __shared__ float Ct[64 * 132];     // 64 rows x 128 cols, stride 132 (33.8 KB)
    int tid = threadIdx.x;
    int wave = tid >> 6;
    int lane = tid & 63;
    int m16 = lane & 15;
    int quad = lane >> 4;
    long row0blk = (long)blockIdx.x * 64;
    long row0 = row0blk + wave * 16;

    half8 af[4];
    {
        long ar = row0 + m16; if (ar >= M) ar = M - 1;
        const _Float16* Ap = (const _Float16*)&A[ar * DP + quad * 8];
#pragma unroll
        for (int k0 = 0; k0 < 4; k0++)
            af[k0] = *(const half8*)(Ap + k0 * 32);
    }

    floatx4 acc[8];
#pragma unroll
    for (int t = 0; t < 8; t++) acc[t] = (floatx4){0.f, 0.f, 0.f, 0.f};

#pragma unroll
    for (int t = 0; t < 8; t++) {
        const _Float16* Wp = &Wt[(t * 16 + m16) * DP + quad * 8];
#pragma unroll
        for (int k0 = 0; k0 < 4; k0++) {
            half8 bf = *(const half8*)(Wp + k0 * 32);
            acc[t] = __builtin_amdgcn_mfma_f32_16x16x32_f16(af[k0], bf, acc[t], 0, 0, 0);
        }
    }

    // stage to LDS (2-way banks at worst)
    int lrow0 = wave * 16 + quad * 4;
#pragma unroll
    for (int t = 0; t < 8; t++) {
#pragma unroll
        for (int r = 0; r < 4; r++)
            Ct[(lrow0 + r) * 132 + t * 16 + m16] = acc[t][r];
    }
    __syncthreads();

    // cooperative coalesced epilogue: 64 rows x 32 float4
    for (int idx = tid; idx < 64 * 32; idx += 256) {
        int lr = idx >> 5, c4 = idx & 31;
        long grow = row0blk + lr;
        if (grow >= M) continue;
        int col = c4 * 4;
        float4 v = *(const float4*)&Ct[lr * 132 + col];
        if (bias && col < Kout) {
            float4 bb = *(const float4*)&bias[col];
            v.x += bb.x; v.y += bb.y; v.z += bb.z; v.w += bb.w;
        }
        if (addendH) {
            uint2 u = *(const uint2*)&addendH[grow * DP + col];
            float2 f01 = __half22float2(*(__half2*)&u.x);
            float2 f23 = __half22float2(*(__half2*)&u.y);
            v.x += f01.x; v.y += f01.y; v.z += f23.x; v.w += f23.y;
        }
        if (relu) {
            v.x = fmaxf(v.x, 0.f); v.y = fmaxf(v.y, 0.f);
            v.z = fmaxf(v.z, 0.f); v.w = fmaxf(v.w, 0.f);
        }
        if (rowscale) {
            float rs = rowscale[grow];
            v.x *= rs; v.y *= rs; v.z *= rs; v.w *= rs;
        }
        if (Ch) {
            __half2 p01 = __floats2half2_rn(v.x, v.y);
            __half2 p23 = __floats2half2_rn(v.z, v.w);
            uint2 u;
            u.x = *(unsigned int*)&p01;
            u.y = *(unsigned int*)&p23;
            *(uint2*)&Ch[grow * DP + col] = u;
        } else {
            *(float4*)&C[grow * DP + col] = v;
        }
    }
}

// ---------------- batchnorm stats ----------------
__global__ void bn_stats_kernel(const float* __restrict__ h, float* __restrict__ sum,
                                float* __restrict__ sq, int n) {
    int col = threadIdx.x;
    float s = 0.f, q = 0.f;
    for (int row = blockIdx.x; row < n; row += gridDim.x) {
        float v = h[(long)row * DP + col];
        s += v;
        q += v * v;
    }
    atomicAdd(&sum[col], s);
    atomicAdd(&sq[col], q);
}

// ---------------- batchnorm apply -> fp16 h ----------------
__global__ void bn_apply_kernel(const float* __restrict__ h, const float* __restrict__ sum,
                                const float* __restrict__ sq, const float* __restrict__ gamma,
                                const float* __restrict__ beta, __half* __restrict__ outH, int n) {
    long i = (long)blockIdx.x * blockDim.x + threadIdx.x;
    if (i >= (long)n * DP) return;
    int c = (int)(i & 127);
    float v = 0.f;
    if (c < DIM) {
        float inv_n = 1.0f / (float)n;
        float mu = sum[c] * inv_n;
        float var = sq[c] * inv_n - mu * mu;
        float rs = rsqrtf(var + EPSBN);
        v = (h[i] - mu) * rs * gamma[c] + beta[c];
    }
    outH[i] = (__half)v;
}

// ---------------- graph boundaries ----------------
__global__ void gbounds_kernel(const int* __restrict__ batch, int* __restrict__ gstart, int n) {
    int g = threadIdx.x;
    int lo = 0, hi = n;
    while (lo < hi) {
        int mid = (lo + hi) >> 1;
        if (batch[mid] < g) lo = mid + 1; else hi = mid;
    }
    gstart[g] = lo;
    if (g == 0) gstart[NGRAPH] = n;
}

// ---------------- global add pool ----------------
__global__ __launch_bounds__(512) void pool_kernel(const float* __restrict__ a,
                                                   const int* __restrict__ gstart,
                                                   float* __restrict__ g) {
    __shared__ float red[512];
    int b = blockIdx.x, tid = threadIdx.x;
    int col = tid & 127;
    int quarter = tid >> 7;
    int lo = gstart[b], hi = gstart[b + 1];
    float s = 0.f;
    for (int r = lo + quarter; r < hi; r += 4)
        s += a[(long)r * DP + col];
    red[tid] = s;
    __syncthreads();
    if (tid < 128)
        g[b * DP + tid] = red[tid] + red[tid + 128] + red[tid + 256] + red[tid + 384];
}

// ---------------- fused MLP head ----------------
__global__ __launch_bounds__(256) void mlp_kernel(
        const float* __restrict__ g,
        const float* __restrict__ Wf1, const float* __restrict__ bf1,
        const float* __restrict__ Wf2, const float* __restrict__ bf2,
        const float* __restrict__ Wf3, const float* __restrict__ bf3,
        const float* __restrict__ Wf4, const float* __restrict__ bf4,
        float* __restrict__ out) {
    __shared__ float a0[100], a1[200], a2[300], a3[200], red[256];
    int b = blockIdx.x, tid = threadIdx.x;
    if (tid < 100) a0[tid] = g[b * DP + tid];
    __syncthreads();
    for (int c = tid; c < 200; c += 256) {
        float s = bf1[c];
        for (int k = 0; k < 100; k++) s += a0[k] * Wf1[k * 200 + c];
        a1[c] = fmaxf(s, 0.f);
    }
    __syncthreads();
    for (int c = tid; c < 300; c += 256) {
        float s = bf2[c];
        for (int k = 0; k < 200; k++) s += a1[k] * Wf2[k * 300 + c];
        a2[c] = fmaxf(s, 0.f);
    }
    __syncthreads();
    for (int c = tid; c < 200; c += 256) {
        float s = bf3[c];
        for (int k = 0; k < 300; k++) s += a2[k] * Wf3[k * 200 + c];
        a3[c] = fmaxf(s, 0.f);
    }
    __syncthreads();
    red[tid] = (tid < 200) ? a3[tid] * Wf4[tid] : 0.f;
    __syncthreads();
    for (int o = 128; o > 0; o >>= 1) {
        if (tid < o) red[tid] += red[tid + o];
        __syncthreads();
    }
    if (tid == 0) out[b] = red[0] + bf4[0];
}

extern "C" void kernel_launch(void* const* d_in, const int* in_sizes, int n_in,
                              void* d_out, int out_size, void* d_ws, size_t ws_size,
                              hipStream_t stream) {
    const float* x      = (const float*)d_in[0];
    const int*   src    = (const int*)d_in[1];
    const int*   dst    = (const int*)d_in[2];
    const int*   batch  = (const int*)d_in[3];
    const float* W1     = (const float*)d_in[4];
    const float* b1     = (const float*)d_in[5];
    const float* W2     = (const float*)d_in[6];
    const float* b2     = (const float*)d_in[7];
    const float* gamma  = (const float*)d_in[8];
    const float* beta   = (const float*)d_in[9];
    const float* Wa_init= (const float*)d_in[10];
    const float* Wa_root= (const float*)d_in[11];
    const float* ba     = (const float*)d_in[12];
    const float* Wf1    = (const float*)d_in[13];
    const float* bf1    = (const float*)d_in[14];
    const float* Wf2    = (const float*)d_in[15];
    const float* bf2    = (const float*)d_in[16];
    const float* Wf3    = (const float*)d_in[17];
    const float* bf3    = (const float*)d_in[18];
    const float* Wf4    = (const float*)d_in[19];
    const float* bf4    = (const float*)d_in[20];
    float* out = (float*)d_out;

    const int n = NNODES;
    const int e = NEDGES;

    char* ws = (char*)d_ws;
    auto carve = [&](size_t bytes) -> void* {
        void* p = (void*)ws;
        ws += (bytes + 255) & ~(size_t)255;
        return p;
    };
    float*  bufB    = (float*)carve((size_t)n * DP * 4);    // fp32: h2 / final a
    __half* bufH    = (__half*)carve((size_t)n * DP * 2);   // prop input
    __half* bufHA   = (__half*)carve((size_t)n * DP * 2);   // prop output / matmul A / addend
    __half* bufHB   = (__half*)carve((size_t)n * DP * 2);   // BN'd h fp16
    _Float16* Wt1   = (_Float16*)carve((size_t)DP * DP * 2);
    _Float16* Wt2   = (_Float16*)carve((size_t)DP * DP * 2);
    _Float16* Wt3   = (_Float16*)carve((size_t)DP * DP * 2);
    _Float16* Wt4   = (_Float16*)carve((size_t)DP * DP * 2);
    int*    off     = (int*)carve((size_t)(n + 1) * 4);
    int*    btotal  = (int*)carve((size_t)NBUK * 4);
    int*    bbase   = (int*)carve((size_t)(NBUK + 1) * 4);
    int*    bcursor = (int*)carve((size_t)NBUK * 4);
    int*    ssorted = (int*)carve((size_t)e * 4);
    int2*   gpairs  = (int2*)carve((size_t)e * 8);
    float*  dinv_sl = (float*)carve((size_t)n * 4);
    float*  dinv_nsl= (float*)carve((size_t)n * 4);
    float*  bnsum   = (float*)carve(DP * 4);
    float*  bnsq    = (float*)carve(DP * 4);
    int*    gstart  = (int*)carve((size_t)(NGRAPH + 1) * 4);
    float*  gpool   = (float*)carve((size_t)NGRAPH * DP * 4);

    const int wblk = (DP * DP + 255) / 256;
    const int nchunk = (e + BINCH - 1) / BINCH;

    // ---- pack weights to fp16 transposed ----
    packW_kernel<<<wblk, 256, 0, stream>>>(W1, Wt1, 128, DIM);
    packW_kernel<<<wblk, 256, 0, stream>>>(W2, Wt2, DIM, DIM);
    packW_kernel<<<wblk, 256, 0, stream>>>(Wa_init, Wt3, DIM, DIM);
    packW_kernel<<<wblk, 256, 0, stream>>>(Wa_root, Wt4, DIM, DIM);

    // ---- build CSR by dst: bucket counts -> scan -> bin -> fused build ----
    hipMemsetAsync(btotal, 0, (size_t)NBUK * 4, stream);
    bin_count_kernel<<<nchunk, 256, 0, stream>>>(dst, btotal, e);
    bucket_scan_kernel<<<1, 512, 0, stream>>>(btotal, bbase, bcursor, e);
    bin_kernel<<<nchunk, 256, 0, stream>>>(src, dst, bcursor, gpairs, e);
    bucket_build_kernel<<<NBUK, 256, 0, stream>>>(gpairs, bbase, off, ssorted, dinv_sl, dinv_nsl, n, e);
    gbounds_kernel<<<1, 512, 0, stream>>>(batch, gstart, n);

    const int prop_blocks = (n + 3) / 4;
    const int mm_blocks = (n + 63) / 64;

    // ---- SGConv 1: pre = x*dinv (fp16); prop; h1' = relu(prop@W1+b1)*dinv -> fp16 ----
    prescale_kernel<<<(int)(((long)n * 32 + 255) / 256), 256, 0, stream>>>(x, dinv_sl, bufH, n);
    prop_kernel<<<prop_blocks, 256, 0, stream>>>(bufH, ssorted, off, dinv_sl, bufHA, n, 1);
    matmul_mfma_kernel<<<mm_blocks, 256, 0, stream>>>(bufHA, Wt1, b1, nullptr, dinv_sl, nullptr, bufH, n, DIM, 1);

    // ---- SGConv 2: prop on fp16 h1'; h2 = relu(prop@W2+b2) (fp32 for BN) ----
    prop_kernel<<<prop_blocks, 256, 0, stream>>>(bufH, ssorted, off, dinv_sl, bufHA, n, 1);
    matmul_mfma_kernel<<<mm_blocks, 256, 0, stream>>>(bufHA, Wt2, b2, nullptr, nullptr, bufB, nullptr, n, DIM, 1);

    // ---- BatchNorm -> fp16 h ----
    hipMemsetAsync(bnsum, 0, DP * 4, stream);
    hipMemsetAsync(bnsq, 0, DP * 4, stream);
    bn_stats_kernel<<<512, 128, 0, stream>>>(bufB, bnsum, bnsq, n);
    bn_apply_kernel<<<(int)(((long)n * DP + 255) / 256), 256, 0, stream>>>(bufB, bnsum, bnsq, gamma, beta, bufHB, n);

    // ---- ARMAConv: t = (h@Wa_init)*dinv_nsl (fp16); prop(no SL); relu(h@Wa_root+ba+t_prop) ----
    matmul_mfma_kernel<<<mm_blocks, 256, 0, stream>>>(bufHB, Wt3, nullptr, nullptr, dinv_nsl, nullptr, bufH, n, DIM, 0);
    prop_kernel<<<prop_blocks, 256, 0, stream>>>(bufH, ssorted, off, dinv_nsl, bufHA, n, 0);
    matmul_mfma_kernel<<<mm_blocks, 256, 0, stream>>>(bufHB, Wt4, ba, bufHA, nullptr, bufB, nullptr, n, DIM, 1);

    // ---- global add pool ----
    pool_kernel<<<NGRAPH, 512, 0, stream>>>(bufB, gstart, gpool);

    // ---- MLP head ----
    mlp_kernel<<<NGRAPH, 256, 0, stream>>>(gpool, Wf1, bf1, Wf2, bf2, Wf3, bf3, Wf4, bf4, out);
}

// Round 11
// 641.939 us; speedup vs baseline: 1.3192x; 1.0792x over previous
//
#include <hip/hip_runtime.h>
#include <hip/hip_fp16.h>

#define NNODES 100000
#define NEDGES 1600000
#define NGRAPH 512
#define DIM    100
#define DP     128
#define EPSBN  1e-5f
#define NBUK   ((NNODES + 255) >> 8)   // 391 dst-buckets of 256 nodes
#define BINCH  8192                    // edges per bin block

typedef _Float16 half8 __attribute__((ext_vector_type(8)));
typedef float floatx4 __attribute__((ext_vector_type(4)));

// ---------------- pass 0: per-chunk bucket counts (LDS), accumulate to global ----------------
__global__ __launch_bounds__(256) void bin_count_kernel(const int* __restrict__ dst,
                                                        int* __restrict__ btotal, int e) {
    __shared__ int lc[NBUK];
    int tid = threadIdx.x;
    int base = blockIdx.x * BINCH;
    int m = e - base; if (m > BINCH) m = BINCH;
    for (int b = tid; b < NBUK; b += 256) lc[b] = 0;
    __syncthreads();
    for (int j = tid; j < m; j += 256)
        atomicAdd(&lc[dst[base + j] >> 8], 1);
    __syncthreads();
    for (int b = tid; b < NBUK; b += 256)
        if (lc[b]) atomicAdd(&btotal[b], lc[b]);
}

// ---------------- bucket exclusive scan -> bases + cursors ----------------
__global__ void bucket_scan_kernel(const int* __restrict__ btotal, int* __restrict__ bbase,
                                   int* __restrict__ bcursor, int e) {
    __shared__ int s[512];
    int tid = threadIdx.x;
    int v = (tid < NBUK) ? btotal[tid] : 0;
    s[tid] = v; __syncthreads();
    for (int o = 1; o < 512; o <<= 1) {
        int t = (tid >= o) ? s[tid - o] : 0;
        __syncthreads();
        s[tid] += t;
        __syncthreads();
    }
    if (tid < NBUK) {
        int base = s[tid] - v;
        bbase[tid] = base;
        bcursor[tid] = base;
    }
    if (tid == 0) bbase[NBUK] = e;
}

// ---------------- pass 1: bin (src,dst) pairs bucket-major with LDS staging ----------------
__global__ __launch_bounds__(256) void bin_kernel(
        const int* __restrict__ src, const int* __restrict__ dst,
        int* __restrict__ bcursor, int2* __restrict__ gpairs, int e) {
    __shared__ int2 lpairs[BINCH];
    __shared__ int lcount[NBUK], lstart[NBUK], lcur[NBUK], gbase[NBUK];
    int tid = threadIdx.x;
    int base = blockIdx.x * BINCH;
    int m = e - base; if (m > BINCH) m = BINCH;

    for (int b = tid; b < NBUK; b += 256) lcount[b] = 0;
    __syncthreads();

    for (int j = tid; j < m; j += 256)
        atomicAdd(&lcount[dst[base + j] >> 8], 1);
    __syncthreads();

    if (tid == 0) {
        int acc = 0;
        for (int b = 0; b < NBUK; b++) {
            lstart[b] = acc;
            lcur[b] = acc;
            acc += lcount[b];
        }
    }
    __syncthreads();

    for (int b = tid; b < NBUK; b += 256)
        gbase[b] = atomicAdd(&bcursor[b], lcount[b]);
    for (int j = tid; j < m; j += 256) {
        int s = src[base + j], d = dst[base + j];
        int p = atomicAdd(&lcur[d >> 8], 1);
        lpairs[p] = make_int2(s, d);
    }
    __syncthreads();

    for (int j = tid; j < m; j += 256) {
        int2 pr = lpairs[j];
        int b = pr.y >> 8;
        gpairs[gbase[b] + (j - lstart[b])] = pr;
    }
}

// ---------------- pass 2: per-bucket degree count + scan + dinv + scatter (fused) ----------------
__global__ __launch_bounds__(256) void bucket_build_kernel(
        const int2* __restrict__ gpairs, const int* __restrict__ bbase,
        int* __restrict__ off, int* __restrict__ ssorted,
        float* __restrict__ dsl, float* __restrict__ dnsl, int n, int e) {
    __shared__ int cnt[256];
    __shared__ int sc[256];
    int b = blockIdx.x, tid = threadIdx.x;
    int node0 = b << 8;
    int e0 = bbase[b], e1 = bbase[b + 1];

    cnt[tid] = 0;
    __syncthreads();
    for (int j = e0 + tid; j < e1; j += 256)
        atomicAdd(&cnt[gpairs[j].y & 255], 1);
    __syncthreads();

    int c = cnt[tid];
    sc[tid] = c; __syncthreads();
    for (int o = 1; o < 256; o <<= 1) {
        int t = (tid >= o) ? sc[tid - o] : 0;
        __syncthreads();
        sc[tid] += t;
        __syncthreads();
    }
    int excl = sc[tid] - c;

    int node = node0 + tid;
    if (node < n) {
        off[node] = e0 + excl;
        float cf = (float)c;
        dsl[node] = rsqrtf(cf + 1.0f);
        dnsl[node] = (c > 0) ? rsqrtf(cf) : 0.0f;
    }
    if (b == NBUK - 1 && tid == 0) off[n] = e;

    __syncthreads();
    cnt[tid] = e0 + excl;   // per-node write cursor
    __syncthreads();
    for (int j = e0 + tid; j < e1; j += 256) {
        int2 pr = gpairs[j];
        int p = atomicAdd(&cnt[pr.y & 255], 1);
        ssorted[p] = pr.x;
    }
}

// ---------------- prescale rows to fp16 ----------------
__global__ void prescale_kernel(const float* __restrict__ x, const float* __restrict__ d,
                                __half* __restrict__ yh, int n) {
    long i = (long)blockIdx.x * blockDim.x + threadIdx.x;
    if (i >= (long)n * 32) return;
    int row = (int)(i >> 5);
    float s = d[row];
    float4 v = ((const float4*)x)[i];
    __half2 p01 = __floats2half2_rn(v.x * s, v.y * s);
    __half2 p23 = __floats2half2_rn(v.z * s, v.w * s);
    uint2 u;
    u.x = *(unsigned int*)&p01;
    u.y = *(unsigned int*)&p23;
    ((uint2*)yh)[i] = u;
}

// ---------------- pack W: fp32 [K,Kout] -> fp16 transposed [128,128] ----------------
__global__ void packW_kernel(const float* __restrict__ W, _Float16* __restrict__ Wt,
                             int K, int Kout) {
    int idx = blockIdx.x * 256 + threadIdx.x;
    if (idx >= DP * DP) return;
    int nn = idx >> 7, k = idx & 127;
    float v = (k < K && nn < Kout) ? W[k * Kout + nn] : 0.f;
    Wt[nn * DP + k] = (_Float16)v;
}

// ---------------- propagation: one wave per node; 16 lanes x 16B per row, 4 edges concurrent ----------------
__global__ __launch_bounds__(256) void prop_kernel(
        const __half* __restrict__ pre, const int* __restrict__ ssorted,
        const int* __restrict__ off, const float* __restrict__ dinv,
        __half* __restrict__ outH, int n, int selfloop) {
    int wave = (blockIdx.x * blockDim.x + threadIdx.x) >> 6;
    int lane = threadIdx.x & 63;
    if (wave >= n) return;
    int e0 = off[wave], e1 = off[wave + 1];
    int deg = e1 - e0;
    int g = lane >> 4;       // edge-group 0..3
    int q = lane & 15;       // 16 lanes x 8 halves = 128 cols

    float acc[8];
#pragma unroll
    for (int i = 0; i < 8; i++) acc[i] = 0.f;

    auto addu = [&](uint4 u) {
        float2 f;
        f = __half22float2(*(__half2*)&u.x); acc[0] += f.x; acc[1] += f.y;
        f = __half22float2(*(__half2*)&u.y); acc[2] += f.x; acc[3] += f.y;
        f = __half22float2(*(__half2*)&u.z); acc[4] += f.x; acc[5] += f.y;
        f = __half22float2(*(__half2*)&u.w); acc[6] += f.x; acc[7] += f.y;
    };
    auto rowptr = [&](int s) -> const uint4* {
        return (const uint4*)&pre[(long)s * DP + q * 8];
    };

    for (int base = 0; base < deg; base += 64) {
        int m = deg - base; if (m > 64) m = 64;
        int sidx = (lane < m) ? ssorted[e0 + base + lane] : 0;
        int j = 0;
        for (; j + 16 <= m; j += 16) {     // 16 edges, 4 dwordx4 loads in flight per lane
            int s0 = __shfl(sidx, j + g);
            int s1 = __shfl(sidx, j + 4 + g);
            int s2 = __shfl(sidx, j + 8 + g);
            int s3 = __shfl(sidx, j + 12 + g);
            uint4 u0 = *rowptr(s0);
            uint4 u1 = *rowptr(s1);
            uint4 u2 = *rowptr(s2);
            uint4 u3 = *rowptr(s3);
            addu(u0); addu(u1); addu(u2); addu(u3);
        }
        for (; j + 4 <= m; j += 4) {       // 4 edges
            int s = __shfl(sidx, j + g);
            addu(*rowptr(s));
        }
        if (j < m) {                       // 1..3 edges: clamp shfl, mask add
            int r = m - j;
            int s = __shfl(sidx, (g < r) ? j + g : j);
            if (g < r) addu(*rowptr(s));
        }
    }

    // combine 4 edge-groups: butterfly over lane bits 4,5
#pragma unroll
    for (int i = 0; i < 8; i++) {
        acc[i] += __shfl_xor(acc[i], 16);
        acc[i] += __shfl_xor(acc[i], 32);
    }

    if (g == 0) {
        float dn = dinv[wave];
        if (selfloop) addu(*rowptr(wave));
        __half2 p0 = __floats2half2_rn(dn * acc[0], dn * acc[1]);
        __half2 p1 = __floats2half2_rn(dn * acc[2], dn * acc[3]);
        __half2 p2 = __floats2half2_rn(dn * acc[4], dn * acc[5]);
        __half2 p3 = __floats2half2_rn(dn * acc[6], dn * acc[7]);
        uint4 u;
        u.x = *(unsigned int*)&p0;
        u.y = *(unsigned int*)&p1;
        u.z = *(unsigned int*)&p2;
        u.w = *(unsigned int*)&p3;
        *(uint4*)&outH[(long)wave * DP + q * 8] = u;
    }
}

// ---------------- MFMA matmul + optional fused BN-stats reduction ----------------
__global__ __launch_bounds__(256) void matmul_mfma_kernel(
        const __half* __restrict__ A, const _Float16* __restrict__ Wt,
        const float* __restrict__ bias, const __half* __restrict__ addendH,
        const float* __restrict__ rowscale,
        float* __restrict__ C, __half* __restrict__ Ch,
        float* __restrict__ bnsum, float* __restrict__ bnsq,
        int M, int Kout, int relu) {
    __shared__ float Ct[64 * 132];     // 64 rows x 128 cols, stride 132 (33.8 KB)
    int tid = threadIdx.x;
    int wave = tid >> 6;
    int lane = tid & 63;
    int m16 = lane & 15;
    int quad = lane >> 4;
    long row0blk = (long)blockIdx.x * 64;
    long row0 = row0blk + wave * 16;

    half8 af[4];
    {
        long ar = row0 + m16; if (ar >= M) ar = M - 1;
        const _Float16* Ap = (const _Float16*)&A[ar * DP + quad * 8];
#pragma unroll
        for (int k0 = 0; k0 < 4; k0++)
            af[k0] = *(const half8*)(Ap + k0 * 32);
    }

    floatx4 acc[8];
#pragma unroll
    for (int t = 0; t < 8; t++) acc[t] = (floatx4){0.f, 0.f, 0.f, 0.f};

#pragma unroll
    for (int t = 0; t < 8; t++) {
        const _Float16* Wp = &Wt[(t * 16 + m16) * DP + quad * 8];
#pragma unroll
        for (int k0 = 0; k0 < 4; k0++) {
            half8 bf = *(const half8*)(Wp + k0 * 32);
            acc[t] = __builtin_amdgcn_mfma_f32_16x16x32_f16(af[k0], bf, acc[t], 0, 0, 0);
        }
    }

    // stage to LDS
    int lrow0 = wave * 16 + quad * 4;
#pragma unroll
    for (int t = 0; t < 8; t++) {
#pragma unroll
        for (int r = 0; r < 4; r++)
            Ct[(lrow0 + r) * 132 + t * 16 + m16] = acc[t][r];
    }
    __syncthreads();

    // cooperative coalesced epilogue: 64 rows x 32 float4 (c4 = tid&31 fixed per thread)
    float s4[4] = {0.f, 0.f, 0.f, 0.f};
    float q4[4] = {0.f, 0.f, 0.f, 0.f};
    for (int idx = tid; idx < 64 * 32; idx += 256) {
        int lr = idx >> 5, c4 = idx & 31;
        long grow = row0blk + lr;
        if (grow >= M) continue;
        int col = c4 * 4;
        float4 v = *(const float4*)&Ct[lr * 132 + col];
        if (bias && col < Kout) {
            float4 bb = *(const float4*)&bias[col];
            v.x += bb.x; v.y += bb.y; v.z += bb.z; v.w += bb.w;
        }
        if (addendH) {
            uint2 u = *(const uint2*)&addendH[grow * DP + col];
            float2 f01 = __half22float2(*(__half2*)&u.x);
            float2 f23 = __half22float2(*(__half2*)&u.y);
            v.x += f01.x; v.y += f01.y; v.z += f23.x; v.w += f23.y;
        }
        if (relu) {
            v.x = fmaxf(v.x, 0.f); v.y = fmaxf(v.y, 0.f);
            v.z = fmaxf(v.z, 0.f); v.w = fmaxf(v.w, 0.f);
        }
        if (rowscale) {
            float rs = rowscale[grow];
            v.x *= rs; v.y *= rs; v.z *= rs; v.w *= rs;
        }
        if (bnsum) {
            s4[0] += v.x; s4[1] += v.y; s4[2] += v.z; s4[3] += v.w;
            q4[0] += v.x * v.x; q4[1] += v.y * v.y; q4[2] += v.z * v.z; q4[3] += v.w * v.w;
        }
        if (Ch) {
            __half2 p01 = __floats2half2_rn(v.x, v.y);
            __half2 p23 = __floats2half2_rn(v.z, v.w);
            uint2 u;
            u.x = *(unsigned int*)&p01;
            u.y = *(unsigned int*)&p23;
            *(uint2*)&Ch[grow * DP + col] = u;
        } else {
            *(float4*)&C[grow * DP + col] = v;
        }
    }

    if (bnsum) {
        // reduce 8 row-groups x 128 cols through reused Ct LDS, then 1 atomic/col/block
        __syncthreads();
        float* scr = Ct;     // [0..1023]=sum, [1024..2047]=sq
        int g = tid >> 5, c4 = tid & 31;
#pragma unroll
        for (int i = 0; i < 4; i++) {
            scr[g * 128 + c4 * 4 + i] = s4[i];
            scr[1024 + g * 128 + c4 * 4 + i] = q4[i];
        }
        __syncthreads();
        if (tid < 128) {
            float ss = 0.f, qq = 0.f;
#pragma unroll
            for (int gg = 0; gg < 8; gg++) {
                ss += scr[gg * 128 + tid];
                qq += scr[1024 + gg * 128 + tid];
            }
            atomicAdd(&bnsum[tid], ss);
            atomicAdd(&bnsq[tid], qq);
        }
    }
}

// ---------------- bn prep: per-column scale/shift from fused stats ----------------
__global__ void bn_prep_kernel(const float* __restrict__ sum, const float* __restrict__ sq,
                               const float* __restrict__ gamma, const float* __restrict__ beta,
                               float* __restrict__ scale, float* __restrict__ shift, int n) {
    int c = threadIdx.x;   // 128
    float sc = 0.f, sh = 0.f;
    if (c < DIM) {
        float inv_n = 1.0f / (float)n;
        float mu = sum[c] * inv_n;
        float var = sq[c] * inv_n - mu * mu;
        float rs = rsqrtf(var + EPSBN);
        sc = rs * gamma[c];
        sh = beta[c] - mu * sc;
    }
    scale[c] = sc;
    shift[c] = sh;
}

// ---------------- bn apply: fp16 in-place, y = h*scale + shift ----------------
__global__ void bn_apply_kernel(__half* __restrict__ h, const float* __restrict__ scale,
                                const float* __restrict__ shift, int n) {
    long i = (long)blockIdx.x * blockDim.x + threadIdx.x;   // one uint4 (8 halves) per thread
    if (i >= (long)n * 16) return;
    int cb = (int)(i & 15) * 8;
    uint4 u = ((const uint4*)h)[i];
    __half2* hp = (__half2*)&u;
    uint4 o;
    __half2* op = (__half2*)&o;
#pragma unroll
    for (int p = 0; p < 4; p++) {
        float2 f = __half22float2(hp[p]);
        int c = cb + p * 2;
        f.x = f.x * scale[c] + shift[c];
        f.y = f.y * scale[c + 1] + shift[c + 1];
        op[p] = __floats2half2_rn(f.x, f.y);
    }
    ((uint4*)h)[i] = o;
}

// ---------------- graph boundaries ----------------
__global__ void gbounds_kernel(const int* __restrict__ batch, int* __restrict__ gstart, int n) {
    int g = threadIdx.x;
    int lo = 0, hi = n;
    while (lo < hi) {
        int mid = (lo + hi) >> 1;
        if (batch[mid] < g) lo = mid + 1; else hi = mid;
    }
    gstart[g] = lo;
    if (g == 0) gstart[NGRAPH] = n;
}

// ---------------- global add pool ----------------
__global__ __launch_bounds__(512) void pool_kernel(const float* __restrict__ a,
                                                   const int* __restrict__ gstart,
                                                   float* __restrict__ g) {
    __shared__ float red[512];
    int b = blockIdx.x, tid = threadIdx.x;
    int col = tid & 127;
    int quarter = tid >> 7;
    int lo = gstart[b], hi = gstart[b + 1];
    float s = 0.f;
    for (int r = lo + quarter; r < hi; r += 4)
        s += a[(long)r * DP + col];
    red[tid] = s;
    __syncthreads();
    if (tid < 128)
        g[b * DP + tid] = red[tid] + red[tid + 128] + red[tid + 256] + red[tid + 384];
}

// ---------------- fused MLP head ----------------
__global__ __launch_bounds__(256) void mlp_kernel(
        const float* __restrict__ g,
        const float* __restrict__ Wf1, const float* __restrict__ bf1,
        const float* __restrict__ Wf2, const float* __restrict__ bf2,
        const float* __restrict__ Wf3, const float* __restrict__ bf3,
        const float* __restrict__ Wf4, const float* __restrict__ bf4,
        float* __restrict__ out) {
    __shared__ float a0[100], a1[200], a2[300], a3[200], red[256];
    int b = blockIdx.x, tid = threadIdx.x;
    if (tid < 100) a0[tid] = g[b * DP + tid];
    __syncthreads();
    for (int c = tid; c < 200; c += 256) {
        float s = bf1[c];
        for (int k = 0; k < 100; k++) s += a0[k] * Wf1[k * 200 + c];
        a1[c] = fmaxf(s, 0.f);
    }
    __syncthreads();
    for (int c = tid; c < 300; c += 256) {
        float s = bf2[c];
        for (int k = 0; k < 200; k++) s += a1[k] * Wf2[k * 300 + c];
        a2[c] = fmaxf(s, 0.f);
    }
    __syncthreads();
    for (int c = tid; c < 200; c += 256) {
        float s = bf3[c];
        for (int k = 0; k < 300; k++) s += a2[k] * Wf3[k * 200 + c];
        a3[c] = fmaxf(s, 0.f);
    }
    __syncthreads();
    red[tid] = (tid < 200) ? a3[tid] * Wf4[tid] : 0.f;
    __syncthreads();
    for (int o = 128; o > 0; o >>= 1) {
        if (tid < o) red[tid] += red[tid + o];
        __syncthreads();
    }
    if (tid == 0) out[b] = red[0] + bf4[0];
}

extern "C" void kernel_launch(void* const* d_in, const int* in_sizes, int n_in,
                              void* d_out, int out_size, void* d_ws, size_t ws_size,
                              hipStream_t stream) {
    const float* x      = (const float*)d_in[0];
    const int*   src    = (const int*)d_in[1];
    const int*   dst    = (const int*)d_in[2];
    const int*   batch  = (const int*)d_in[3];
    const float* W1     = (const float*)d_in[4];
    const float* b1     = (const float*)d_in[5];
    const float* W2     = (const float*)d_in[6];
    const float* b2     = (const float*)d_in[7];
    const float* gamma  = (const float*)d_in[8];
    const float* beta   = (const float*)d_in[9];
    const float* Wa_init= (const float*)d_in[10];
    const float* Wa_root= (const float*)d_in[11];
    const float* ba     = (const float*)d_in[12];
    const float* Wf1    = (const float*)d_in[13];
    const float* bf1    = (const float*)d_in[14];
    const float* Wf2    = (const float*)d_in[15];
    const float* bf2    = (const float*)d_in[16];
    const float* Wf3    = (const float*)d_in[17];
    const float* bf3    = (const float*)d_in[18];
    const float* Wf4    = (const float*)d_in[19];
    const float* bf4    = (const float*)d_in[20];
    float* out = (float*)d_out;

    const int n = NNODES;
    const int e = NEDGES;

    char* ws = (char*)d_ws;
    auto carve = [&](size_t bytes) -> void* {
        void* p = (void*)ws;
        ws += (bytes + 255) & ~(size_t)255;
        return p;
    };
    float*  bufB    = (float*)carve((size_t)n * DP * 4);    // fp32: final ARMA output
    __half* bufH    = (__half*)carve((size_t)n * DP * 2);   // prop input
    __half* bufHA   = (__half*)carve((size_t)n * DP * 2);   // prop output / matmul A / addend
    __half* bufHB   = (__half*)carve((size_t)n * DP * 2);   // h2 -> BN'd h fp16
    _Float16* Wt1   = (_Float16*)carve((size_t)DP * DP * 2);
    _Float16* Wt2   = (_Float16*)carve((size_t)DP * DP * 2);
    _Float16* Wt3   = (_Float16*)carve((size_t)DP * DP * 2);
    _Float16* Wt4   = (_Float16*)carve((size_t)DP * DP * 2);
    int*    off     = (int*)carve((size_t)(n + 1) * 4);
    int*    btotal  = (int*)carve((size_t)NBUK * 4);
    int*    bbase   = (int*)carve((size_t)(NBUK + 1) * 4);
    int*    bcursor = (int*)carve((size_t)NBUK * 4);
    int*    ssorted = (int*)carve((size_t)e * 4);
    int2*   gpairs  = (int2*)carve((size_t)e * 8);
    float*  dinv_sl = (float*)carve((size_t)n * 4);
    float*  dinv_nsl= (float*)carve((size_t)n * 4);
    float*  bnsum   = (float*)carve(DP * 4);
    float*  bnsq    = (float*)carve(DP * 4);
    float*  bnscale = (float*)carve(DP * 4);
    float*  bnshift = (float*)carve(DP * 4);
    int*    gstart  = (int*)carve((size_t)(NGRAPH + 1) * 4);
    float*  gpool   = (float*)carve((size_t)NGRAPH * DP * 4);

    const int wblk = (DP * DP + 255) / 256;
    const int nchunk = (e + BINCH - 1) / BINCH;

    // ---- pack weights to fp16 transposed ----
    packW_kernel<<<wblk, 256, 0, stream>>>(W1, Wt1, 128, DIM);
    packW_kernel<<<wblk, 256, 0, stream>>>(W2, Wt2, DIM, DIM);
    packW_kernel<<<wblk, 256, 0, stream>>>(Wa_init, Wt3, DIM, DIM);
    packW_kernel<<<wblk, 256, 0, stream>>>(Wa_root, Wt4, DIM, DIM);

    // ---- build CSR by dst: bucket counts -> scan -> bin -> fused build ----
    hipMemsetAsync(btotal, 0, (size_t)NBUK * 4, stream);
    hipMemsetAsync(bnsum, 0, DP * 4, stream);
    hipMemsetAsync(bnsq, 0, DP * 4, stream);
    bin_count_kernel<<<nchunk, 256, 0, stream>>>(dst, btotal, e);
    bucket_scan_kernel<<<1, 512, 0, stream>>>(btotal, bbase, bcursor, e);
    bin_kernel<<<nchunk, 256, 0, stream>>>(src, dst, bcursor, gpairs, e);
    bucket_build_kernel<<<NBUK, 256, 0, stream>>>(gpairs, bbase, off, ssorted, dinv_sl, dinv_nsl, n, e);
    gbounds_kernel<<<1, 512, 0, stream>>>(batch, gstart, n);

    const int prop_blocks = (n + 3) / 4;
    const int mm_blocks = (n + 63) / 64;

    // ---- SGConv 1: pre = x*dinv (fp16); prop; h1' = relu(prop@W1+b1)*dinv -> fp16 ----
    prescale_kernel<<<(int)(((long)n * 32 + 255) / 256), 256, 0, stream>>>(x, dinv_sl, bufH, n);
    prop_kernel<<<prop_blocks, 256, 0, stream>>>(bufH, ssorted, off, dinv_sl, bufHA, n, 1);
    matmul_mfma_kernel<<<mm_blocks, 256, 0, stream>>>(bufHA, Wt1, b1, nullptr, dinv_sl, nullptr, bufH, nullptr, nullptr, n, DIM, 1);

    // ---- SGConv 2: prop; h2 = relu(prop@W2+b2) -> fp16 with fused BN stats ----
    prop_kernel<<<prop_blocks, 256, 0, stream>>>(bufH, ssorted, off, dinv_sl, bufHA, n, 1);
    matmul_mfma_kernel<<<mm_blocks, 256, 0, stream>>>(bufHA, Wt2, b2, nullptr, nullptr, nullptr, bufHB, bnsum, bnsq, n, DIM, 1);

    // ---- BatchNorm: prep scale/shift, apply fp16 in-place ----
    bn_prep_kernel<<<1, 128, 0, stream>>>(bnsum, bnsq, gamma, beta, bnscale, bnshift, n);
    bn_apply_kernel<<<(int)(((long)n * 16 + 255) / 256), 256, 0, stream>>>(bufHB, bnscale, bnshift, n);

    // ---- ARMAConv: t = (h@Wa_init)*dinv_nsl (fp16); prop(no SL); relu(h@Wa_root+ba+t_prop) ----
    matmul_mfma_kernel<<<mm_blocks, 256, 0, stream>>>(bufHB, Wt3, nullptr, nullptr, dinv_nsl, nullptr, bufH, nullptr, nullptr, n, DIM, 0);
    prop_kernel<<<prop_blocks, 256, 0, stream>>>(bufH, ssorted, off, dinv_nsl, bufHA, n, 0);
    matmul_mfma_kernel<<<mm_blocks, 256, 0, stream>>>(bufHB, Wt4, ba, bufHA, nullptr, bufB, nullptr, nullptr, nullptr, n, DIM, 1);

    // ---- global add pool ----
    pool_kernel<<<NGRAPH, 512, 0, stream>>>(bufB, gstart, gpool);

    // ---- MLP head ----
    mlp_kernel<<<NGRAPH, 256, 0, stream>>>(gpool, Wf1, bf1, Wf2, bf2, Wf3, bf3, Wf4, bf4, out);
}

// Round 12
// 564.083 us; speedup vs baseline: 1.5013x; 1.1380x over previous
//
#include <hip/hip_runtime.h>
#include <hip/hip_fp16.h>

#define NNODES 100000
#define NEDGES 1600000
#define NGRAPH 512
#define DIM    100
#define DP     128
#define EPSBN  1e-5f
#define NBUK   ((NNODES + 255) >> 8)   // 391 dst-buckets of 256 nodes
#define BINCH  8192                    // edges per bin block

typedef _Float16 half8 __attribute__((ext_vector_type(8)));
typedef float floatx4 __attribute__((ext_vector_type(4)));

// ---------------- pass 0: per-chunk bucket counts (LDS), accumulate to global ----------------
__global__ __launch_bounds__(256) void bin_count_kernel(const int* __restrict__ dst,
                                                        int* __restrict__ btotal, int e) {
    __shared__ int lc[NBUK];
    int tid = threadIdx.x;
    int base = blockIdx.x * BINCH;
    int m = e - base; if (m > BINCH) m = BINCH;
    for (int b = tid; b < NBUK; b += 256) lc[b] = 0;
    __syncthreads();
    for (int j = tid; j < m; j += 256)
        atomicAdd(&lc[dst[base + j] >> 8], 1);
    __syncthreads();
    for (int b = tid; b < NBUK; b += 256)
        if (lc[b]) atomicAdd(&btotal[b], lc[b]);
}

// ---------------- bucket exclusive scan -> bases + cursors ----------------
__global__ void bucket_scan_kernel(const int* __restrict__ btotal, int* __restrict__ bbase,
                                   int* __restrict__ bcursor, int e) {
    __shared__ int s[512];
    int tid = threadIdx.x;
    int v = (tid < NBUK) ? btotal[tid] : 0;
    s[tid] = v; __syncthreads();
    for (int o = 1; o < 512; o <<= 1) {
        int t = (tid >= o) ? s[tid - o] : 0;
        __syncthreads();
        s[tid] += t;
        __syncthreads();
    }
    if (tid < NBUK) {
        int base = s[tid] - v;
        bbase[tid] = base;
        bcursor[tid] = base;
    }
    if (tid == 0) bbase[NBUK] = e;
}

// ---------------- pass 1: bin (src,dst) pairs bucket-major with LDS staging ----------------
__global__ __launch_bounds__(256) void bin_kernel(
        const int* __restrict__ src, const int* __restrict__ dst,
        int* __restrict__ bcursor, int2* __restrict__ gpairs, int e) {
    __shared__ int2 lpairs[BINCH];
    __shared__ int lcount[NBUK], lstart[NBUK], lcur[NBUK], gbase[NBUK];
    int tid = threadIdx.x;
    int base = blockIdx.x * BINCH;
    int m = e - base; if (m > BINCH) m = BINCH;

    for (int b = tid; b < NBUK; b += 256) lcount[b] = 0;
    __syncthreads();

    for (int j = tid; j < m; j += 256)
        atomicAdd(&lcount[dst[base + j] >> 8], 1);
    __syncthreads();

    if (tid == 0) {
        int acc = 0;
        for (int b = 0; b < NBUK; b++) {
            lstart[b] = acc;
            lcur[b] = acc;
            acc += lcount[b];
        }
    }
    __syncthreads();

    for (int b = tid; b < NBUK; b += 256)
        gbase[b] = atomicAdd(&bcursor[b], lcount[b]);
    for (int j = tid; j < m; j += 256) {
        int s = src[base + j], d = dst[base + j];
        int p = atomicAdd(&lcur[d >> 8], 1);
        lpairs[p] = make_int2(s, d);
    }
    __syncthreads();

    for (int j = tid; j < m; j += 256) {
        int2 pr = lpairs[j];
        int b = pr.y >> 8;
        gpairs[gbase[b] + (j - lstart[b])] = pr;
    }
}

// ---------------- pass 2: per-bucket degree count + scan + dinv + scatter (fused) ----------------
__global__ __launch_bounds__(256) void bucket_build_kernel(
        const int2* __restrict__ gpairs, const int* __restrict__ bbase,
        int* __restrict__ off, int* __restrict__ ssorted,
        float* __restrict__ dsl, float* __restrict__ dnsl, int n, int e) {
    __shared__ int cnt[256];
    __shared__ int sc[256];
    int b = blockIdx.x, tid = threadIdx.x;
    int node0 = b << 8;
    int e0 = bbase[b], e1 = bbase[b + 1];

    cnt[tid] = 0;
    __syncthreads();
    for (int j = e0 + tid; j < e1; j += 256)
        atomicAdd(&cnt[gpairs[j].y & 255], 1);
    __syncthreads();

    int c = cnt[tid];
    sc[tid] = c; __syncthreads();
    for (int o = 1; o < 256; o <<= 1) {
        int t = (tid >= o) ? sc[tid - o] : 0;
        __syncthreads();
        sc[tid] += t;
        __syncthreads();
    }
    int excl = sc[tid] - c;

    int node = node0 + tid;
    if (node < n) {
        off[node] = e0 + excl;
        float cf = (float)c;
        dsl[node] = rsqrtf(cf + 1.0f);
        dnsl[node] = (c > 0) ? rsqrtf(cf) : 0.0f;
    }
    if (b == NBUK - 1 && tid == 0) off[n] = e;

    __syncthreads();
    cnt[tid] = e0 + excl;   // per-node write cursor
    __syncthreads();
    for (int j = e0 + tid; j < e1; j += 256) {
        int2 pr = gpairs[j];
        int p = atomicAdd(&cnt[pr.y & 255], 1);
        ssorted[p] = pr.x;
    }
}

// ---------------- prescale rows to fp16 ----------------
__global__ void prescale_kernel(const float* __restrict__ x, const float* __restrict__ d,
                                __half* __restrict__ yh, int n) {
    long i = (long)blockIdx.x * blockDim.x + threadIdx.x;
    if (i >= (long)n * 32) return;
    int row = (int)(i >> 5);
    float s = d[row];
    float4 v = ((const float4*)x)[i];
    __half2 p01 = __floats2half2_rn(v.x * s, v.y * s);
    __half2 p23 = __floats2half2_rn(v.z * s, v.w * s);
    uint2 u;
    u.x = *(unsigned int*)&p01;
    u.y = *(unsigned int*)&p23;
    ((uint2*)yh)[i] = u;
}

// ---------------- pack W into MFMA fragment order ----------------
// WtF[((t*4+k0)*64 + lane)*8 + j] = W[k0*32 + (lane>>4)*8 + j][t*16 + (lane&15)]
// => every B-frag load is lane-linear (lane i reads byte i*16): perfectly coalesced.
__global__ void packW_kernel(const float* __restrict__ W, _Float16* __restrict__ WtF,
                             int K, int Kout) {
    int idx = blockIdx.x * 256 + threadIdx.x;
    if (idx >= DP * DP) return;
    int j = idx & 7;
    int l = (idx >> 3) & 63;
    int c = idx >> 9;              // 0..31 = t*4+k0
    int t = c >> 2, k0 = c & 3;
    int nn = t * 16 + (l & 15);
    int k = k0 * 32 + (l >> 4) * 8 + j;
    float v = (k < K && nn < Kout) ? W[k * Kout + nn] : 0.f;
    WtF[idx] = (_Float16)v;
}

// ---------------- propagation: one wave per node; 16 lanes x 16B per row, 4 edges concurrent ----------------
__global__ __launch_bounds__(256) void prop_kernel(
        const __half* __restrict__ pre, const int* __restrict__ ssorted,
        const int* __restrict__ off, const float* __restrict__ dinv,
        __half* __restrict__ outH, int n, int selfloop) {
    int wave = (blockIdx.x * blockDim.x + threadIdx.x) >> 6;
    int lane = threadIdx.x & 63;
    if (wave >= n) return;
    int e0 = off[wave], e1 = off[wave + 1];
    int deg = e1 - e0;
    int g = lane >> 4;
    int q = lane & 15;

    float acc[8];
#pragma unroll
    for (int i = 0; i < 8; i++) acc[i] = 0.f;

    auto addu = [&](uint4 u) {
        float2 f;
        f = __half22float2(*(__half2*)&u.x); acc[0] += f.x; acc[1] += f.y;
        f = __half22float2(*(__half2*)&u.y); acc[2] += f.x; acc[3] += f.y;
        f = __half22float2(*(__half2*)&u.z); acc[4] += f.x; acc[5] += f.y;
        f = __half22float2(*(__half2*)&u.w); acc[6] += f.x; acc[7] += f.y;
    };
    auto rowptr = [&](int s) -> const uint4* {
        return (const uint4*)&pre[(long)s * DP + q * 8];
    };

    for (int base = 0; base < deg; base += 64) {
        int m = deg - base; if (m > 64) m = 64;
        int sidx = (lane < m) ? ssorted[e0 + base + lane] : 0;
        int j = 0;
        for (; j + 16 <= m; j += 16) {
            int s0 = __shfl(sidx, j + g);
            int s1 = __shfl(sidx, j + 4 + g);
            int s2 = __shfl(sidx, j + 8 + g);
            int s3 = __shfl(sidx, j + 12 + g);
            uint4 u0 = *rowptr(s0);
            uint4 u1 = *rowptr(s1);
            uint4 u2 = *rowptr(s2);
            uint4 u3 = *rowptr(s3);
            addu(u0); addu(u1); addu(u2); addu(u3);
        }
        for (; j + 4 <= m; j += 4) {
            int s = __shfl(sidx, j + g);
            addu(*rowptr(s));
        }
        if (j < m) {
            int r = m - j;
            int s = __shfl(sidx, (g < r) ? j + g : j);
            if (g < r) addu(*rowptr(s));
        }
    }

#pragma unroll
    for (int i = 0; i < 8; i++) {
        acc[i] += __shfl_xor(acc[i], 16);
        acc[i] += __shfl_xor(acc[i], 32);
    }

    if (g == 0) {
        float dn = dinv[wave];
        if (selfloop) addu(*rowptr(wave));
        __half2 p0 = __floats2half2_rn(dn * acc[0], dn * acc[1]);
        __half2 p1 = __floats2half2_rn(dn * acc[2], dn * acc[3]);
        __half2 p2 = __floats2half2_rn(dn * acc[4], dn * acc[5]);
        __half2 p3 = __floats2half2_rn(dn * acc[6], dn * acc[7]);
        uint4 u;
        u.x = *(unsigned int*)&p0;
        u.y = *(unsigned int*)&p1;
        u.z = *(unsigned int*)&p2;
        u.w = *(unsigned int*)&p3;
        *(uint4*)&outH[(long)wave * DP + q * 8] = u;
    }
}

// ---------------- ARMA prop: out = relu(dinv*sum + R), fp16 out ----------------
__global__ __launch_bounds__(256) void prop_arma_kernel(
        const __half* __restrict__ pre, const int* __restrict__ ssorted,
        const int* __restrict__ off, const float* __restrict__ dinv,
        const __half* __restrict__ R, __half* __restrict__ outH, int n) {
    int wave = (blockIdx.x * blockDim.x + threadIdx.x) >> 6;
    int lane = threadIdx.x & 63;
    if (wave >= n) return;
    int e0 = off[wave], e1 = off[wave + 1];
    int deg = e1 - e0;
    int g = lane >> 4;
    int q = lane & 15;

    float acc[8];
#pragma unroll
    for (int i = 0; i < 8; i++) acc[i] = 0.f;

    auto addu = [&](uint4 u) {
        float2 f;
        f = __half22float2(*(__half2*)&u.x); acc[0] += f.x; acc[1] += f.y;
        f = __half22float2(*(__half2*)&u.y); acc[2] += f.x; acc[3] += f.y;
        f = __half22float2(*(__half2*)&u.z); acc[4] += f.x; acc[5] += f.y;
        f = __half22float2(*(__half2*)&u.w); acc[6] += f.x; acc[7] += f.y;
    };
    auto rowptr = [&](int s) -> const uint4* {
        return (const uint4*)&pre[(long)s * DP + q * 8];
    };

    for (int base = 0; base < deg; base += 64) {
        int m = deg - base; if (m > 64) m = 64;
        int sidx = (lane < m) ? ssorted[e0 + base + lane] : 0;
        int j = 0;
        for (; j + 16 <= m; j += 16) {
            int s0 = __shfl(sidx, j + g);
            int s1 = __shfl(sidx, j + 4 + g);
            int s2 = __shfl(sidx, j + 8 + g);
            int s3 = __shfl(sidx, j + 12 + g);
            uint4 u0 = *rowptr(s0);
            uint4 u1 = *rowptr(s1);
            uint4 u2 = *rowptr(s2);
            uint4 u3 = *rowptr(s3);
            addu(u0); addu(u1); addu(u2); addu(u3);
        }
        for (; j + 4 <= m; j += 4) {
            int s = __shfl(sidx, j + g);
            addu(*rowptr(s));
        }
        if (j < m) {
            int r = m - j;
            int s = __shfl(sidx, (g < r) ? j + g : j);
            if (g < r) addu(*rowptr(s));
        }
    }

#pragma unroll
    for (int i = 0; i < 8; i++) {
        acc[i] += __shfl_xor(acc[i], 16);
        acc[i] += __shfl_xor(acc[i], 32);
    }

    if (g == 0) {
        float dn = dinv[wave];
        uint4 r4 = *(const uint4*)&R[(long)wave * DP + q * 8];
        float rr[8];
        float2 f;
        f = __half22float2(*(__half2*)&r4.x); rr[0] = f.x; rr[1] = f.y;
        f = __half22float2(*(__half2*)&r4.y); rr[2] = f.x; rr[3] = f.y;
        f = __half22float2(*(__half2*)&r4.z); rr[4] = f.x; rr[5] = f.y;
        f = __half22float2(*(__half2*)&r4.w); rr[6] = f.x; rr[7] = f.y;
        float o[8];
#pragma unroll
        for (int i = 0; i < 8; i++) o[i] = fmaxf(dn * acc[i] + rr[i], 0.f);
        __half2 p0 = __floats2half2_rn(o[0], o[1]);
        __half2 p1 = __floats2half2_rn(o[2], o[3]);
        __half2 p2 = __floats2half2_rn(o[4], o[5]);
        __half2 p3 = __floats2half2_rn(o[6], o[7]);
        uint4 u;
        u.x = *(unsigned int*)&p0;
        u.y = *(unsigned int*)&p1;
        u.z = *(unsigned int*)&p2;
        u.w = *(unsigned int*)&p3;
        *(uint4*)&outH[(long)wave * DP + q * 8] = u;
    }
}

// ---------------- MFMA matmul: frag-order W, all 32 B-frags preloaded; fp16 out ----------------
__global__ __launch_bounds__(256, 2) void matmul_mfma_kernel(
        const __half* __restrict__ A, const _Float16* __restrict__ WtF,
        const float* __restrict__ bias, const float* __restrict__ rowscale,
        __half* __restrict__ Ch, float* __restrict__ bnsum, float* __restrict__ bnsq,
        int M, int Kout, int relu) {
    __shared__ float Ct[64 * 132];
    int tid = threadIdx.x;
    int wave = tid >> 6;
    int lane = tid & 63;
    int m16 = lane & 15;
    int quad = lane >> 4;
    long row0blk = (long)blockIdx.x * 64;
    long row0 = row0blk + wave * 16;

    // all 32 B-frags: lane-linear loads, one long burst
    const half8* Bp = (const half8*)WtF;
    half8 bf[32];
#pragma unroll
    for (int c = 0; c < 32; c++) bf[c] = Bp[c * 64 + lane];

    half8 af[4];
    {
        long ar = row0 + m16; if (ar >= M) ar = M - 1;
        const _Float16* Ap = (const _Float16*)&A[ar * DP + quad * 8];
#pragma unroll
        for (int k0 = 0; k0 < 4; k0++)
            af[k0] = *(const half8*)(Ap + k0 * 32);
    }

    floatx4 acc[8];
#pragma unroll
    for (int t = 0; t < 8; t++) acc[t] = (floatx4){0.f, 0.f, 0.f, 0.f};

#pragma unroll
    for (int c = 0; c < 32; c++)
        acc[c >> 2] = __builtin_amdgcn_mfma_f32_16x16x32_f16(af[c & 3], bf[c], acc[c >> 2], 0, 0, 0);

    int lrow0 = wave * 16 + quad * 4;
#pragma unroll
    for (int t = 0; t < 8; t++)
#pragma unroll
        for (int r = 0; r < 4; r++)
            Ct[(lrow0 + r) * 132 + t * 16 + m16] = acc[t][r];
    __syncthreads();

    float s4[4] = {0.f, 0.f, 0.f, 0.f};
    float q4[4] = {0.f, 0.f, 0.f, 0.f};
    for (int idx = tid; idx < 64 * 32; idx += 256) {
        int lr = idx >> 5, c4 = idx & 31;
        long grow = row0blk + lr;
        if (grow >= M) continue;
        int col = c4 * 4;
        float4 v = *(const float4*)&Ct[lr * 132 + col];
        if (bias && col < Kout) {
            float4 bb = *(const float4*)&bias[col];
            v.x += bb.x; v.y += bb.y; v.z += bb.z; v.w += bb.w;
        }
        if (relu) {
            v.x = fmaxf(v.x, 0.f); v.y = fmaxf(v.y, 0.f);
            v.z = fmaxf(v.z, 0.f); v.w = fmaxf(v.w, 0.f);
        }
        if (rowscale) {
            float rs = rowscale[grow];
            v.x *= rs; v.y *= rs; v.z *= rs; v.w *= rs;
        }
        if (bnsum) {
            s4[0] += v.x; s4[1] += v.y; s4[2] += v.z; s4[3] += v.w;
            q4[0] += v.x * v.x; q4[1] += v.y * v.y; q4[2] += v.z * v.z; q4[3] += v.w * v.w;
        }
        __half2 p01 = __floats2half2_rn(v.x, v.y);
        __half2 p23 = __floats2half2_rn(v.z, v.w);
        uint2 u;
        u.x = *(unsigned int*)&p01;
        u.y = *(unsigned int*)&p23;
        *(uint2*)&Ch[grow * DP + col] = u;
    }

    if (bnsum) {
        __syncthreads();
        float* scr = Ct;
        int g = tid >> 5, c4 = tid & 31;
#pragma unroll
        for (int i = 0; i < 4; i++) {
            scr[g * 128 + c4 * 4 + i] = s4[i];
            scr[1024 + g * 128 + c4 * 4 + i] = q4[i];
        }
        __syncthreads();
        if (tid < 128) {
            float ss = 0.f, qq = 0.f;
#pragma unroll
            for (int gg = 0; gg < 8; gg++) {
                ss += scr[gg * 128 + tid];
                qq += scr[1024 + gg * 128 + tid];
            }
            atomicAdd(&bnsum[tid], ss);
            atomicAdd(&bnsq[tid], qq);
        }
    }
}

// ---------------- dual MFMA matmul: P1 = A@W3 * rowscale -> Ch1 ; R = A@W4 + ba -> ChR ----------------
__global__ __launch_bounds__(256, 2) void matmul_dual_kernel(
        const __half* __restrict__ A, const _Float16* __restrict__ WtF3,
        const _Float16* __restrict__ WtF4, const float* __restrict__ ba,
        const float* __restrict__ rowscale,
        __half* __restrict__ Ch1, __half* __restrict__ ChR, int M, int Kout) {
    __shared__ float Ct[64 * 132];
    int tid = threadIdx.x;
    int wave = tid >> 6;
    int lane = tid & 63;
    int m16 = lane & 15;
    int quad = lane >> 4;
    long row0blk = (long)blockIdx.x * 64;
    long row0 = row0blk + wave * 16;

    half8 af[4];
    {
        long ar = row0 + m16; if (ar >= M) ar = M - 1;
        const _Float16* Ap = (const _Float16*)&A[ar * DP + quad * 8];
#pragma unroll
        for (int k0 = 0; k0 < 4; k0++)
            af[k0] = *(const half8*)(Ap + k0 * 32);
    }

    const half8* Bp3 = (const half8*)WtF3;
    const half8* Bp4 = (const half8*)WtF4;
    floatx4 acc3[8], acc4[8];
#pragma unroll
    for (int t = 0; t < 8; t++) {
        acc3[t] = (floatx4){0.f, 0.f, 0.f, 0.f};
        acc4[t] = (floatx4){0.f, 0.f, 0.f, 0.f};
    }

#pragma unroll
    for (int t = 0; t < 8; t++) {
        half8 b3[4], b4[4];
#pragma unroll
        for (int k0 = 0; k0 < 4; k0++) {
            b3[k0] = Bp3[(t * 4 + k0) * 64 + lane];
            b4[k0] = Bp4[(t * 4 + k0) * 64 + lane];
        }
#pragma unroll
        for (int k0 = 0; k0 < 4; k0++) {
            acc3[t] = __builtin_amdgcn_mfma_f32_16x16x32_f16(af[k0], b3[k0], acc3[t], 0, 0, 0);
            acc4[t] = __builtin_amdgcn_mfma_f32_16x16x32_f16(af[k0], b4[k0], acc4[t], 0, 0, 0);
        }
    }

    int lrow0 = wave * 16 + quad * 4;

    // --- P1: rowscale, no bias/relu ---
#pragma unroll
    for (int t = 0; t < 8; t++)
#pragma unroll
        for (int r = 0; r < 4; r++)
            Ct[(lrow0 + r) * 132 + t * 16 + m16] = acc3[t][r];
    __syncthreads();
    for (int idx = tid; idx < 64 * 32; idx += 256) {
        int lr = idx >> 5, c4 = idx & 31;
        long grow = row0blk + lr;
        if (grow >= M) continue;
        int col = c4 * 4;
        float4 v = *(const float4*)&Ct[lr * 132 + col];
        float rs = rowscale[grow];
        v.x *= rs; v.y *= rs; v.z *= rs; v.w *= rs;
        __half2 p01 = __floats2half2_rn(v.x, v.y);
        __half2 p23 = __floats2half2_rn(v.z, v.w);
        uint2 u;
        u.x = *(unsigned int*)&p01;
        u.y = *(unsigned int*)&p23;
        *(uint2*)&Ch1[grow * DP + col] = u;
    }
    __syncthreads();

    // --- R: + ba, no relu ---
#pragma unroll
    for (int t = 0; t < 8; t++)
#pragma unroll
        for (int r = 0; r < 4; r++)
            Ct[(lrow0 + r) * 132 + t * 16 + m16] = acc4[t][r];
    __syncthreads();
    for (int idx = tid; idx < 64 * 32; idx += 256) {
        int lr = idx >> 5, c4 = idx & 31;
        long grow = row0blk + lr;
        if (grow >= M) continue;
        int col = c4 * 4;
        float4 v = *(const float4*)&Ct[lr * 132 + col];
        if (col < Kout) {
            float4 bb = *(const float4*)&ba[col];
            v.x += bb.x; v.y += bb.y; v.z += bb.z; v.w += bb.w;
        }
        __half2 p01 = __floats2half2_rn(v.x, v.y);
        __half2 p23 = __floats2half2_rn(v.z, v.w);
        uint2 u;
        u.x = *(unsigned int*)&p01;
        u.y = *(unsigned int*)&p23;
        *(uint2*)&ChR[grow * DP + col] = u;
    }
}

// ---------------- bn prep ----------------
__global__ void bn_prep_kernel(const float* __restrict__ sum, const float* __restrict__ sq,
                               const float* __restrict__ gamma, const float* __restrict__ beta,
                               float* __restrict__ scale, float* __restrict__ shift, int n) {
    int c = threadIdx.x;
    float sc = 0.f, sh = 0.f;
    if (c < DIM) {
        float inv_n = 1.0f / (float)n;
        float mu = sum[c] * inv_n;
        float var = sq[c] * inv_n - mu * mu;
        float rs = rsqrtf(var + EPSBN);
        sc = rs * gamma[c];
        sh = beta[c] - mu * sc;
    }
    scale[c] = sc;
    shift[c] = sh;
}

// ---------------- bn apply: fp16 in-place ----------------
__global__ void bn_apply_kernel(__half* __restrict__ h, const float* __restrict__ scale,
                                const float* __restrict__ shift, int n) {
    long i = (long)blockIdx.x * blockDim.x + threadIdx.x;
    if (i >= (long)n * 16) return;
    int cb = (int)(i & 15) * 8;
    uint4 u = ((const uint4*)h)[i];
    __half2* hp = (__half2*)&u;
    uint4 o;
    __half2* op = (__half2*)&o;
#pragma unroll
    for (int p = 0; p < 4; p++) {
        float2 f = __half22float2(hp[p]);
        int c = cb + p * 2;
        f.x = f.x * scale[c] + shift[c];
        f.y = f.y * scale[c + 1] + shift[c + 1];
        op[p] = __floats2half2_rn(f.x, f.y);
    }
    ((uint4*)h)[i] = o;
}

// ---------------- graph boundaries ----------------
__global__ void gbounds_kernel(const int* __restrict__ batch, int* __restrict__ gstart, int n) {
    int g = threadIdx.x;
    int lo = 0, hi = n;
    while (lo < hi) {
        int mid = (lo + hi) >> 1;
        if (batch[mid] < g) lo = mid + 1; else hi = mid;
    }
    gstart[g] = lo;
    if (g == 0) gstart[NGRAPH] = n;
}

// ---------------- global add pool (fp16 input) ----------------
__global__ __launch_bounds__(512) void pool_kernel(const __half* __restrict__ a,
                                                   const int* __restrict__ gstart,
                                                   float* __restrict__ g) {
    __shared__ float2 red[512];
    int b = blockIdx.x, tid = threadIdx.x;
    int col2 = tid & 63;          // half2 index: cols col2*2, col2*2+1
    int rgrp = tid >> 6;          // 8 row strides
    int lo = gstart[b], hi = gstart[b + 1];
    float2 s = make_float2(0.f, 0.f);
    for (int r = lo + rgrp; r < hi; r += 8) {
        __half2 h = *(const __half2*)&a[(long)r * DP + col2 * 2];
        float2 f = __half22float2(h);
        s.x += f.x; s.y += f.y;
    }
    red[tid] = s;
    __syncthreads();
    if (tid < 64) {
        float2 t = make_float2(0.f, 0.f);
#pragma unroll
        for (int gg = 0; gg < 8; gg++) {
            float2 v = red[gg * 64 + tid];
            t.x += v.x; t.y += v.y;
        }
        *(float2*)&g[b * DP + tid * 2] = t;
    }
}

// ---------------- fused MLP head ----------------
__global__ __launch_bounds__(256) void mlp_kernel(
        const float* __restrict__ g,
        const float* __restrict__ Wf1, const float* __restrict__ bf1,
        const float* __restrict__ Wf2, const float* __restrict__ bf2,
        const float* __restrict__ Wf3, const float* __restrict__ bf3,
        const float* __restrict__ Wf4, const float* __restrict__ bf4,
        float* __restrict__ out) {
    __shared__ float a0[100], a1[200], a2[300], a3[200], red[256];
    int b = blockIdx.x, tid = threadIdx.x;
    if (tid < 100) a0[tid] = g[b * DP + tid];
    __syncthreads();
    for (int c = tid; c < 200; c += 256) {
        float s = bf1[c];
        for (int k = 0; k < 100; k++) s += a0[k] * Wf1[k * 200 + c];
        a1[c] = fmaxf(s, 0.f);
    }
    __syncthreads();
    for (int c = tid; c < 300; c += 256) {
        float s = bf2[c];
        for (int k = 0; k < 200; k++) s += a1[k] * Wf2[k * 300 + c];
        a2[c] = fmaxf(s, 0.f);
    }
    __syncthreads();
    for (int c = tid; c < 200; c += 256) {
        float s = bf3[c];
        for (int k = 0; k < 300; k++) s += a2[k] * Wf3[k * 200 + c];
        a3[c] = fmaxf(s, 0.f);
    }
    __syncthreads();
    red[tid] = (tid < 200) ? a3[tid] * Wf4[tid] : 0.f;
    __syncthreads();
    for (int o = 128; o > 0; o >>= 1) {
        if (tid < o) red[tid] += red[tid + o];
        __syncthreads();
    }
    if (tid == 0) out[b] = red[0] + bf4[0];
}

extern "C" void kernel_launch(void* const* d_in, const int* in_sizes, int n_in,
                              void* d_out, int out_size, void* d_ws, size_t ws_size,
                              hipStream_t stream) {
    const float* x      = (const float*)d_in[0];
    const int*   src    = (const int*)d_in[1];
    const int*   dst    = (const int*)d_in[2];
    const int*   batch  = (const int*)d_in[3];
    const float* W1     = (const float*)d_in[4];
    const float* b1     = (const float*)d_in[5];
    const float* W2     = (const float*)d_in[6];
    const float* b2     = (const float*)d_in[7];
    const float* gamma  = (const float*)d_in[8];
    const float* beta   = (const float*)d_in[9];
    const float* Wa_init= (const float*)d_in[10];
    const float* Wa_root= (const float*)d_in[11];
    const float* ba     = (const float*)d_in[12];
    const float* Wf1    = (const float*)d_in[13];
    const float* bf1    = (const float*)d_in[14];
    const float* Wf2    = (const float*)d_in[15];
    const float* bf2    = (const float*)d_in[16];
    const float* Wf3    = (const float*)d_in[17];
    const float* bf3    = (const float*)d_in[18];
    const float* Wf4    = (const float*)d_in[19];
    const float* bf4    = (const float*)d_in[20];
    float* out = (float*)d_out;

    const int n = NNODES;
    const int e = NEDGES;

    char* ws = (char*)d_ws;
    auto carve = [&](size_t bytes) -> void* {
        void* p = (void*)ws;
        ws += (bytes + 255) & ~(size_t)255;
        return p;
    };
    __half* bufH    = (__half*)carve((size_t)n * DP * 2);   // prop input / P1
    __half* bufHA   = (__half*)carve((size_t)n * DP * 2);   // prop output / matmul A
    __half* bufHB   = (__half*)carve((size_t)n * DP * 2);   // h2 -> BN'd h
    __half* bufR    = (__half*)carve((size_t)n * DP * 2);   // ARMA root partial
    __half* bufHC   = (__half*)carve((size_t)n * DP * 2);   // final a (fp16)
    _Float16* Wt1   = (_Float16*)carve((size_t)DP * DP * 2);
    _Float16* Wt2   = (_Float16*)carve((size_t)DP * DP * 2);
    _Float16* Wt3   = (_Float16*)carve((size_t)DP * DP * 2);
    _Float16* Wt4   = (_Float16*)carve((size_t)DP * DP * 2);
    int*    off     = (int*)carve((size_t)(n + 1) * 4);
    int*    btotal  = (int*)carve((size_t)NBUK * 4);
    int*    bbase   = (int*)carve((size_t)(NBUK + 1) * 4);
    int*    bcursor = (int*)carve((size_t)NBUK * 4);
    int*    ssorted = (int*)carve((size_t)e * 4);
    int2*   gpairs  = (int2*)carve((size_t)e * 8);
    float*  dinv_sl = (float*)carve((size_t)n * 4);
    float*  dinv_nsl= (float*)carve((size_t)n * 4);
    float*  bnsum   = (float*)carve(DP * 4);
    float*  bnsq    = (float*)carve(DP * 4);
    float*  bnscale = (float*)carve(DP * 4);
    float*  bnshift = (float*)carve(DP * 4);
    int*    gstart  = (int*)carve((size_t)(NGRAPH + 1) * 4);
    float*  gpool   = (float*)carve((size_t)NGRAPH * DP * 4);

    const int wblk = (DP * DP + 255) / 256;
    const int nchunk = (e + BINCH - 1) / BINCH;

    // ---- pack weights to MFMA fragment order ----
    packW_kernel<<<wblk, 256, 0, stream>>>(W1, Wt1, 128, DIM);
    packW_kernel<<<wblk, 256, 0, stream>>>(W2, Wt2, DIM, DIM);
    packW_kernel<<<wblk, 256, 0, stream>>>(Wa_init, Wt3, DIM, DIM);
    packW_kernel<<<wblk, 256, 0, stream>>>(Wa_root, Wt4, DIM, DIM);

    // ---- build CSR by dst ----
    hipMemsetAsync(btotal, 0, (size_t)NBUK * 4, stream);
    hipMemsetAsync(bnsum, 0, DP * 4, stream);
    hipMemsetAsync(bnsq, 0, DP * 4, stream);
    bin_count_kernel<<<nchunk, 256, 0, stream>>>(dst, btotal, e);
    bucket_scan_kernel<<<1, 512, 0, stream>>>(btotal, bbase, bcursor, e);
    bin_kernel<<<nchunk, 256, 0, stream>>>(src, dst, bcursor, gpairs, e);
    bucket_build_kernel<<<NBUK, 256, 0, stream>>>(gpairs, bbase, off, ssorted, dinv_sl, dinv_nsl, n, e);
    gbounds_kernel<<<1, 512, 0, stream>>>(batch, gstart, n);

    const int prop_blocks = (n + 3) / 4;
    const int mm_blocks = (n + 63) / 64;

    // ---- SGConv 1 ----
    prescale_kernel<<<(int)(((long)n * 32 + 255) / 256), 256, 0, stream>>>(x, dinv_sl, bufH, n);
    prop_kernel<<<prop_blocks, 256, 0, stream>>>(bufH, ssorted, off, dinv_sl, bufHA, n, 1);
    matmul_mfma_kernel<<<mm_blocks, 256, 0, stream>>>(bufHA, Wt1, b1, dinv_sl, bufH, nullptr, nullptr, n, DIM, 1);

    // ---- SGConv 2 (+fused BN stats) ----
    prop_kernel<<<prop_blocks, 256, 0, stream>>>(bufH, ssorted, off, dinv_sl, bufHA, n, 1);
    matmul_mfma_kernel<<<mm_blocks, 256, 0, stream>>>(bufHA, Wt2, b2, nullptr, bufHB, bnsum, bnsq, n, DIM, 1);

    // ---- BatchNorm ----
    bn_prep_kernel<<<1, 128, 0, stream>>>(bnsum, bnsq, gamma, beta, bnscale, bnshift, n);
    bn_apply_kernel<<<(int)(((long)n * 16 + 255) / 256), 256, 0, stream>>>(bufHB, bnscale, bnshift, n);

    // ---- ARMAConv: dual matmul (P1, R), then prop with fused add+relu ----
    matmul_dual_kernel<<<mm_blocks, 256, 0, stream>>>(bufHB, Wt3, Wt4, ba, dinv_nsl, bufH, bufR, n, DIM);
    prop_arma_kernel<<<prop_blocks, 256, 0, stream>>>(bufH, ssorted, off, dinv_nsl, bufR, bufHC, n);

    // ---- global add pool (fp16 in) ----
    pool_kernel<<<NGRAPH, 512, 0, stream>>>(bufHC, gstart, gpool);

    // ---- MLP head ----
    mlp_kernel<<<NGRAPH, 256, 0, stream>>>(gpool, Wf1, bf1, Wf2, bf2, Wf3, bf3, Wf4, bf4, out);
}

// Round 13
// 545.903 us; speedup vs baseline: 1.5513x; 1.0333x over previous
//
#include <hip/hip_runtime.h>
#include <hip/hip_fp16.h>

#define NNODES 100000
#define NEDGES 1600000
#define NGRAPH 512
#define DIM    100
#define DP     128
#define EPSBN  1e-5f
#define NBUK   ((NNODES + 255) >> 8)
#define BINCH  8192

typedef _Float16 half8 __attribute__((ext_vector_type(8)));
typedef float floatx4 __attribute__((ext_vector_type(4)));

// ---------------- pass 0: per-chunk bucket counts ----------------
__global__ __launch_bounds__(256) void bin_count_kernel(const int* __restrict__ dst,
                                                        int* __restrict__ btotal, int e) {
    __shared__ int lc[NBUK];
    int tid = threadIdx.x;
    int base = blockIdx.x * BINCH;
    int m = e - base; if (m > BINCH) m = BINCH;
    for (int b = tid; b < NBUK; b += 256) lc[b] = 0;
    __syncthreads();
    for (int j = tid; j < m; j += 256)
        atomicAdd(&lc[dst[base + j] >> 8], 1);
    __syncthreads();
    for (int b = tid; b < NBUK; b += 256)
        if (lc[b]) atomicAdd(&btotal[b], lc[b]);
}

// ---------------- bucket exclusive scan ----------------
__global__ void bucket_scan_kernel(const int* __restrict__ btotal, int* __restrict__ bbase,
                                   int* __restrict__ bcursor, int e) {
    __shared__ int s[512];
    int tid = threadIdx.x;
    int v = (tid < NBUK) ? btotal[tid] : 0;
    s[tid] = v; __syncthreads();
    for (int o = 1; o < 512; o <<= 1) {
        int t = (tid >= o) ? s[tid - o] : 0;
        __syncthreads();
        s[tid] += t;
        __syncthreads();
    }
    if (tid < NBUK) {
        int base = s[tid] - v;
        bbase[tid] = base;
        bcursor[tid] = base;
    }
    if (tid == 0) bbase[NBUK] = e;
}

// ---------------- pass 1: bin pairs bucket-major ----------------
__global__ __launch_bounds__(256) void bin_kernel(
        const int* __restrict__ src, const int* __restrict__ dst,
        int* __restrict__ bcursor, int2* __restrict__ gpairs, int e) {
    __shared__ int2 lpairs[BINCH];
    __shared__ int lcount[NBUK], lstart[NBUK], lcur[NBUK], gbase[NBUK];
    int tid = threadIdx.x;
    int base = blockIdx.x * BINCH;
    int m = e - base; if (m > BINCH) m = BINCH;

    for (int b = tid; b < NBUK; b += 256) lcount[b] = 0;
    __syncthreads();
    for (int j = tid; j < m; j += 256)
        atomicAdd(&lcount[dst[base + j] >> 8], 1);
    __syncthreads();
    if (tid == 0) {
        int acc = 0;
        for (int b = 0; b < NBUK; b++) {
            lstart[b] = acc;
            lcur[b] = acc;
            acc += lcount[b];
        }
    }
    __syncthreads();
    for (int b = tid; b < NBUK; b += 256)
        gbase[b] = atomicAdd(&bcursor[b], lcount[b]);
    for (int j = tid; j < m; j += 256) {
        int s = src[base + j], d = dst[base + j];
        int p = atomicAdd(&lcur[d >> 8], 1);
        lpairs[p] = make_int2(s, d);
    }
    __syncthreads();
    for (int j = tid; j < m; j += 256) {
        int2 pr = lpairs[j];
        int b = pr.y >> 8;
        gpairs[gbase[b] + (j - lstart[b])] = pr;
    }
}

// ---------------- pass 2: fused per-bucket build ----------------
__global__ __launch_bounds__(256) void bucket_build_kernel(
        const int2* __restrict__ gpairs, const int* __restrict__ bbase,
        int* __restrict__ off, int* __restrict__ ssorted,
        float* __restrict__ dsl, float* __restrict__ dnsl, int n, int e) {
    __shared__ int cnt[256];
    __shared__ int sc[256];
    int b = blockIdx.x, tid = threadIdx.x;
    int node0 = b << 8;
    int e0 = bbase[b], e1 = bbase[b + 1];

    cnt[tid] = 0;
    __syncthreads();
    for (int j = e0 + tid; j < e1; j += 256)
        atomicAdd(&cnt[gpairs[j].y & 255], 1);
    __syncthreads();

    int c = cnt[tid];
    sc[tid] = c; __syncthreads();
    for (int o = 1; o < 256; o <<= 1) {
        int t = (tid >= o) ? sc[tid - o] : 0;
        __syncthreads();
        sc[tid] += t;
        __syncthreads();
    }
    int excl = sc[tid] - c;

    int node = node0 + tid;
    if (node < n) {
        off[node] = e0 + excl;
        float cf = (float)c;
        dsl[node] = rsqrtf(cf + 1.0f);
        dnsl[node] = (c > 0) ? rsqrtf(cf) : 0.0f;
    }
    if (b == NBUK - 1 && tid == 0) off[n] = e;

    __syncthreads();
    cnt[tid] = e0 + excl;
    __syncthreads();
    for (int j = e0 + tid; j < e1; j += 256) {
        int2 pr = gpairs[j];
        int p = atomicAdd(&cnt[pr.y & 255], 1);
        ssorted[p] = pr.x;
    }
}

// ---------------- prescale rows to fp16 ----------------
__global__ void prescale_kernel(const float* __restrict__ x, const float* __restrict__ d,
                                __half* __restrict__ yh, int n) {
    long i = (long)blockIdx.x * blockDim.x + threadIdx.x;
    if (i >= (long)n * 32) return;
    int row = (int)(i >> 5);
    float s = d[row];
    float4 v = ((const float4*)x)[i];
    __half2 p01 = __floats2half2_rn(v.x * s, v.y * s);
    __half2 p23 = __floats2half2_rn(v.z * s, v.w * s);
    uint2 u;
    u.x = *(unsigned int*)&p01;
    u.y = *(unsigned int*)&p23;
    ((uint2*)yh)[i] = u;
}

// ---------------- pack all 4 W into MFMA fragment order (one launch) ----------------
__global__ void packW4_kernel(const float* __restrict__ W1, const float* __restrict__ W2,
                              const float* __restrict__ W3, const float* __restrict__ W4,
                              _Float16* __restrict__ Wt1, _Float16* __restrict__ Wt2,
                              _Float16* __restrict__ Wt3, _Float16* __restrict__ Wt4) {
    int which = blockIdx.x >> 6;          // 64 blocks per weight
    int idx = (blockIdx.x & 63) * 256 + threadIdx.x;
    const float* W = (which == 0) ? W1 : (which == 1) ? W2 : (which == 2) ? W3 : W4;
    _Float16* Wt  = (which == 0) ? Wt1 : (which == 1) ? Wt2 : (which == 2) ? Wt3 : Wt4;
    int K = (which == 0) ? 128 : DIM;
    int j = idx & 7;
    int l = (idx >> 3) & 63;
    int c = idx >> 9;
    int t = c >> 2, k0 = c & 3;
    int nn = t * 16 + (l & 15);
    int k = k0 * 32 + (l >> 4) * 8 + j;
    float v = (k < K && nn < DIM) ? W[k * DIM + nn] : 0.f;
    if (which == 0) v = (k < 128 && nn < DIM) ? W[k * DIM + nn] : 0.f;
    Wt[idx] = (_Float16)v;
}

// ---------------- propagation ----------------
__global__ __launch_bounds__(256) void prop_kernel(
        const __half* __restrict__ pre, const int* __restrict__ ssorted,
        const int* __restrict__ off, const float* __restrict__ dinv,
        __half* __restrict__ outH, int n, int selfloop) {
    int wave = (blockIdx.x * blockDim.x + threadIdx.x) >> 6;
    int lane = threadIdx.x & 63;
    if (wave >= n) return;
    int e0 = off[wave], e1 = off[wave + 1];
    int deg = e1 - e0;
    int g = lane >> 4;
    int q = lane & 15;

    float acc[8];
#pragma unroll
    for (int i = 0; i < 8; i++) acc[i] = 0.f;

    auto addu = [&](uint4 u) {
        float2 f;
        f = __half22float2(*(__half2*)&u.x); acc[0] += f.x; acc[1] += f.y;
        f = __half22float2(*(__half2*)&u.y); acc[2] += f.x; acc[3] += f.y;
        f = __half22float2(*(__half2*)&u.z); acc[4] += f.x; acc[5] += f.y;
        f = __half22float2(*(__half2*)&u.w); acc[6] += f.x; acc[7] += f.y;
    };
    auto rowptr = [&](int s) -> const uint4* {
        return (const uint4*)&pre[(long)s * DP + q * 8];
    };

    for (int base = 0; base < deg; base += 64) {
        int m = deg - base; if (m > 64) m = 64;
        int sidx = (lane < m) ? ssorted[e0 + base + lane] : 0;
        int j = 0;
        for (; j + 16 <= m; j += 16) {
            int s0 = __shfl(sidx, j + g);
            int s1 = __shfl(sidx, j + 4 + g);
            int s2 = __shfl(sidx, j + 8 + g);
            int s3 = __shfl(sidx, j + 12 + g);
            uint4 u0 = *rowptr(s0);
            uint4 u1 = *rowptr(s1);
            uint4 u2 = *rowptr(s2);
            uint4 u3 = *rowptr(s3);
            addu(u0); addu(u1); addu(u2); addu(u3);
        }
        for (; j + 4 <= m; j += 4) {
            int s = __shfl(sidx, j + g);
            addu(*rowptr(s));
        }
        if (j < m) {
            int r = m - j;
            int s = __shfl(sidx, (g < r) ? j + g : j);
            if (g < r) addu(*rowptr(s));
        }
    }

#pragma unroll
    for (int i = 0; i < 8; i++) {
        acc[i] += __shfl_xor(acc[i], 16);
        acc[i] += __shfl_xor(acc[i], 32);
    }

    if (g == 0) {
        float dn = dinv[wave];
        if (selfloop) addu(*rowptr(wave));
        __half2 p0 = __floats2half2_rn(dn * acc[0], dn * acc[1]);
        __half2 p1 = __floats2half2_rn(dn * acc[2], dn * acc[3]);
        __half2 p2 = __floats2half2_rn(dn * acc[4], dn * acc[5]);
        __half2 p3 = __floats2half2_rn(dn * acc[6], dn * acc[7]);
        uint4 u;
        u.x = *(unsigned int*)&p0;
        u.y = *(unsigned int*)&p1;
        u.z = *(unsigned int*)&p2;
        u.w = *(unsigned int*)&p3;
        *(uint4*)&outH[(long)wave * DP + q * 8] = u;
    }
}

// ---------------- ARMA prop: out = relu(dinv*sum + R) ----------------
__global__ __launch_bounds__(256) void prop_arma_kernel(
        const __half* __restrict__ pre, const int* __restrict__ ssorted,
        const int* __restrict__ off, const float* __restrict__ dinv,
        const __half* __restrict__ R, __half* __restrict__ outH, int n) {
    int wave = (blockIdx.x * blockDim.x + threadIdx.x) >> 6;
    int lane = threadIdx.x & 63;
    if (wave >= n) return;
    int e0 = off[wave], e1 = off[wave + 1];
    int deg = e1 - e0;
    int g = lane >> 4;
    int q = lane & 15;

    float acc[8];
#pragma unroll
    for (int i = 0; i < 8; i++) acc[i] = 0.f;

    auto addu = [&](uint4 u) {
        float2 f;
        f = __half22float2(*(__half2*)&u.x); acc[0] += f.x; acc[1] += f.y;
        f = __half22float2(*(__half2*)&u.y); acc[2] += f.x; acc[3] += f.y;
        f = __half22float2(*(__half2*)&u.z); acc[4] += f.x; acc[5] += f.y;
        f = __half22float2(*(__half2*)&u.w); acc[6] += f.x; acc[7] += f.y;
    };
    auto rowptr = [&](int s) -> const uint4* {
        return (const uint4*)&pre[(long)s * DP + q * 8];
    };

    for (int base = 0; base < deg; base += 64) {
        int m = deg - base; if (m > 64) m = 64;
        int sidx = (lane < m) ? ssorted[e0 + base + lane] : 0;
        int j = 0;
        for (; j + 16 <= m; j += 16) {
            int s0 = __shfl(sidx, j + g);
            int s1 = __shfl(sidx, j + 4 + g);
            int s2 = __shfl(sidx, j + 8 + g);
            int s3 = __shfl(sidx, j + 12 + g);
            uint4 u0 = *rowptr(s0);
            uint4 u1 = *rowptr(s1);
            uint4 u2 = *rowptr(s2);
            uint4 u3 = *rowptr(s3);
            addu(u0); addu(u1); addu(u2); addu(u3);
        }
        for (; j + 4 <= m; j += 4) {
            int s = __shfl(sidx, j + g);
            addu(*rowptr(s));
        }
        if (j < m) {
            int r = m - j;
            int s = __shfl(sidx, (g < r) ? j + g : j);
            if (g < r) addu(*rowptr(s));
        }
    }

#pragma unroll
    for (int i = 0; i < 8; i++) {
        acc[i] += __shfl_xor(acc[i], 16);
        acc[i] += __shfl_xor(acc[i], 32);
    }

    if (g == 0) {
        float dn = dinv[wave];
        uint4 r4 = *(const uint4*)&R[(long)wave * DP + q * 8];
        float rr[8];
        float2 f;
        f = __half22float2(*(__half2*)&r4.x); rr[0] = f.x; rr[1] = f.y;
        f = __half22float2(*(__half2*)&r4.y); rr[2] = f.x; rr[3] = f.y;
        f = __half22float2(*(__half2*)&r4.z); rr[4] = f.x; rr[5] = f.y;
        f = __half22float2(*(__half2*)&r4.w); rr[6] = f.x; rr[7] = f.y;
        float o[8];
#pragma unroll
        for (int i = 0; i < 8; i++) o[i] = fmaxf(dn * acc[i] + rr[i], 0.f);
        __half2 p0 = __floats2half2_rn(o[0], o[1]);
        __half2 p1 = __floats2half2_rn(o[2], o[3]);
        __half2 p2 = __floats2half2_rn(o[4], o[5]);
        __half2 p3 = __floats2half2_rn(o[6], o[7]);
        uint4 u;
        u.x = *(unsigned int*)&p0;
        u.y = *(unsigned int*)&p1;
        u.z = *(unsigned int*)&p2;
        u.w = *(unsigned int*)&p3;
        *(uint4*)&outH[(long)wave * DP + q * 8] = u;
    }
}

// ---------------- MFMA matmul: B staged in LDS (shared by all waves), LDS reused as Ct ----------------
__global__ __launch_bounds__(256) void matmul_mfma_kernel(
        const __half* __restrict__ A, const _Float16* __restrict__ WtF,
        const float* __restrict__ bias, const float* __restrict__ rowscale,
        __half* __restrict__ Ch, float* __restrict__ bnsum, float* __restrict__ bnsq,
        int M, int Kout, int relu) {
    __shared__ char smraw[64 * 132 * 4];    // 33792 B: B-stage (32 KB) then Ct
    _Float16* Bs = (_Float16*)smraw;
    float* Ct = (float*)smraw;
    int tid = threadIdx.x;
    int wave = tid >> 6;
    int lane = tid & 63;
    int m16 = lane & 15;
    int quad = lane >> 4;
    long row0blk = (long)blockIdx.x * 64;
    long row0 = row0blk + wave * 16;

    // stage B: 32 KB coalesced
    {
        const uint4* s = (const uint4*)WtF;
        uint4* d = (uint4*)Bs;
        for (int i = tid; i < 2048; i += 256) d[i] = s[i];
    }

    half8 af[4];
    {
        long ar = row0 + m16; if (ar >= M) ar = M - 1;
        const _Float16* Ap = (const _Float16*)&A[ar * DP + quad * 8];
#pragma unroll
        for (int k0 = 0; k0 < 4; k0++)
            af[k0] = *(const half8*)(Ap + k0 * 32);
    }
    __syncthreads();

    floatx4 acc[8];
#pragma unroll
    for (int t = 0; t < 8; t++) acc[t] = (floatx4){0.f, 0.f, 0.f, 0.f};

#pragma unroll
    for (int c = 0; c < 32; c++) {
        half8 bf = *(const half8*)&Bs[(c * 64 + lane) * 8];
        acc[c >> 2] = __builtin_amdgcn_mfma_f32_16x16x32_f16(af[c & 3], bf, acc[c >> 2], 0, 0, 0);
    }
    __syncthreads();   // all B reads done before Ct overwrite

    int lrow0 = wave * 16 + quad * 4;
#pragma unroll
    for (int t = 0; t < 8; t++)
#pragma unroll
        for (int r = 0; r < 4; r++)
            Ct[(lrow0 + r) * 132 + t * 16 + m16] = acc[t][r];
    __syncthreads();

    float s4[4] = {0.f, 0.f, 0.f, 0.f};
    float q4[4] = {0.f, 0.f, 0.f, 0.f};
    for (int idx = tid; idx < 64 * 32; idx += 256) {
        int lr = idx >> 5, c4 = idx & 31;
        long grow = row0blk + lr;
        if (grow >= M) continue;
        int col = c4 * 4;
        float4 v = *(const float4*)&Ct[lr * 132 + col];
        if (bias && col < Kout) {
            float4 bb = *(const float4*)&bias[col];
            v.x += bb.x; v.y += bb.y; v.z += bb.z; v.w += bb.w;
        }
        if (relu) {
            v.x = fmaxf(v.x, 0.f); v.y = fmaxf(v.y, 0.f);
            v.z = fmaxf(v.z, 0.f); v.w = fmaxf(v.w, 0.f);
        }
        if (rowscale) {
            float rs = rowscale[grow];
            v.x *= rs; v.y *= rs; v.z *= rs; v.w *= rs;
        }
        if (bnsum) {
            s4[0] += v.x; s4[1] += v.y; s4[2] += v.z; s4[3] += v.w;
            q4[0] += v.x * v.x; q4[1] += v.y * v.y; q4[2] += v.z * v.z; q4[3] += v.w * v.w;
        }
        __half2 p01 = __floats2half2_rn(v.x, v.y);
        __half2 p23 = __floats2half2_rn(v.z, v.w);
        uint2 u;
        u.x = *(unsigned int*)&p01;
        u.y = *(unsigned int*)&p23;
        *(uint2*)&Ch[grow * DP + col] = u;
    }

    if (bnsum) {
        __syncthreads();
        float* scr = Ct;
        int g = tid >> 5, c4 = tid & 31;
#pragma unroll
        for (int i = 0; i < 4; i++) {
            scr[g * 128 + c4 * 4 + i] = s4[i];
            scr[1024 + g * 128 + c4 * 4 + i] = q4[i];
        }
        __syncthreads();
        if (tid < 128) {
            float ss = 0.f, qq = 0.f;
#pragma unroll
            for (int gg = 0; gg < 8; gg++) {
                ss += scr[gg * 128 + tid];
                qq += scr[1024 + gg * 128 + tid];
            }
            atomicAdd(&bnsum[tid], ss);
            atomicAdd(&bnsq[tid], qq);
        }
    }
}

// ---------------- dual MFMA matmul with fused BN on A: P1 = BN(A)@W3*rowscale ; R = BN(A)@W4 + ba ----------------
__global__ __launch_bounds__(256) void matmul_dual_kernel(
        const __half* __restrict__ A, const _Float16* __restrict__ WtF3,
        const _Float16* __restrict__ WtF4, const float* __restrict__ ba,
        const float* __restrict__ rowscale,
        const float* __restrict__ bnscale, const float* __restrict__ bnshift,
        __half* __restrict__ Ch1, __half* __restrict__ ChR, int M, int Kout) {
    __shared__ char smraw[64 * 132 * 4];
    _Float16* Bs = (_Float16*)smraw;
    float* Ct = (float*)smraw;
    int tid = threadIdx.x;
    int wave = tid >> 6;
    int lane = tid & 63;
    int m16 = lane & 15;
    int quad = lane >> 4;
    long row0blk = (long)blockIdx.x * 64;
    long row0 = row0blk + wave * 16;

    // A-frags with fused BatchNorm (per-column scale/shift; pad cols have scale=shift=0)
    half8 af[4];
    {
        long ar = row0 + m16; if (ar >= M) ar = M - 1;
        const _Float16* Ap = (const _Float16*)&A[ar * DP + quad * 8];
#pragma unroll
        for (int k0 = 0; k0 < 4; k0++) {
            half8 h = *(const half8*)(Ap + k0 * 32);
            int c0 = quad * 8 + k0 * 32;
            float4 sc0 = *(const float4*)&bnscale[c0];
            float4 sc1 = *(const float4*)&bnscale[c0 + 4];
            float4 sh0 = *(const float4*)&bnshift[c0];
            float4 sh1 = *(const float4*)&bnshift[c0 + 4];
            half8 o;
            o[0] = (_Float16)((float)h[0] * sc0.x + sh0.x);
            o[1] = (_Float16)((float)h[1] * sc0.y + sh0.y);
            o[2] = (_Float16)((float)h[2] * sc0.z + sh0.z);
            o[3] = (_Float16)((float)h[3] * sc0.w + sh0.w);
            o[4] = (_Float16)((float)h[4] * sc1.x + sh1.x);
            o[5] = (_Float16)((float)h[5] * sc1.y + sh1.y);
            o[6] = (_Float16)((float)h[6] * sc1.z + sh1.z);
            o[7] = (_Float16)((float)h[7] * sc1.w + sh1.w);
            af[k0] = o;
        }
    }

    floatx4 acc3[8], acc4[8];
#pragma unroll
    for (int t = 0; t < 8; t++) {
        acc3[t] = (floatx4){0.f, 0.f, 0.f, 0.f};
        acc4[t] = (floatx4){0.f, 0.f, 0.f, 0.f};
    }

    // --- W3 pass ---
    {
        const uint4* s = (const uint4*)WtF3;
        uint4* d = (uint4*)Bs;
        for (int i = tid; i < 2048; i += 256) d[i] = s[i];
    }
    __syncthreads();
#pragma unroll
    for (int c = 0; c < 32; c++) {
        half8 bf = *(const half8*)&Bs[(c * 64 + lane) * 8];
        acc3[c >> 2] = __builtin_amdgcn_mfma_f32_16x16x32_f16(af[c & 3], bf, acc3[c >> 2], 0, 0, 0);
    }
    __syncthreads();

    // --- W4 pass ---
    {
        const uint4* s = (const uint4*)WtF4;
        uint4* d = (uint4*)Bs;
        for (int i = tid; i < 2048; i += 256) d[i] = s[i];
    }
    __syncthreads();
#pragma unroll
    for (int c = 0; c < 32; c++) {
        half8 bf = *(const half8*)&Bs[(c * 64 + lane) * 8];
        acc4[c >> 2] = __builtin_amdgcn_mfma_f32_16x16x32_f16(af[c & 3], bf, acc4[c >> 2], 0, 0, 0);
    }
    __syncthreads();

    int lrow0 = wave * 16 + quad * 4;

    // --- P1 epilogue: rowscale only ---
#pragma unroll
    for (int t = 0; t < 8; t++)
#pragma unroll
        for (int r = 0; r < 4; r++)
            Ct[(lrow0 + r) * 132 + t * 16 + m16] = acc3[t][r];
    __syncthreads();
    for (int idx = tid; idx < 64 * 32; idx += 256) {
        int lr = idx >> 5, c4 = idx & 31;
        long grow = row0blk + lr;
        if (grow >= M) continue;
        int col = c4 * 4;
        float4 v = *(const float4*)&Ct[lr * 132 + col];
        float rs = rowscale[grow];
        v.x *= rs; v.y *= rs; v.z *= rs; v.w *= rs;
        __half2 p01 = __floats2half2_rn(v.x, v.y);
        __half2 p23 = __floats2half2_rn(v.z, v.w);
        uint2 u;
        u.x = *(unsigned int*)&p01;
        u.y = *(unsigned int*)&p23;
        *(uint2*)&Ch1[grow * DP + col] = u;
    }
    __syncthreads();

    // --- R epilogue: +ba ---
#pragma unroll
    for (int t = 0; t < 8; t++)
#pragma unroll
        for (int r = 0; r < 4; r++)
            Ct[(lrow0 + r) * 132 + t * 16 + m16] = acc4[t][r];
    __syncthreads();
    for (int idx = tid; idx < 64 * 32; idx += 256) {
        int lr = idx >> 5, c4 = idx & 31;
        long grow = row0blk + lr;
        if (grow >= M) continue;
        int col = c4 * 4;
        float4 v = *(const float4*)&Ct[lr * 132 + col];
        if (col < Kout) {
            float4 bb = *(const float4*)&ba[col];
            v.x += bb.x; v.y += bb.y; v.z += bb.z; v.w += bb.w;
        }
        __half2 p01 = __floats2half2_rn(v.x, v.y);
        __half2 p23 = __floats2half2_rn(v.z, v.w);
        uint2 u;
        u.x = *(unsigned int*)&p01;
        u.y = *(unsigned int*)&p23;
        *(uint2*)&ChR[grow * DP + col] = u;
    }
}

// ---------------- bn prep ----------------
__global__ void bn_prep_kernel(const float* __restrict__ sum, const float* __restrict__ sq,
                               const float* __restrict__ gamma, const float* __restrict__ beta,
                               float* __restrict__ scale, float* __restrict__ shift, int n) {
    int c = threadIdx.x;
    float sc = 0.f, sh = 0.f;
    if (c < DIM) {
        float inv_n = 1.0f / (float)n;
        float mu = sum[c] * inv_n;
        float var = sq[c] * inv_n - mu * mu;
        float rs = rsqrtf(var + EPSBN);
        sc = rs * gamma[c];
        sh = beta[c] - mu * sc;
    }
    scale[c] = sc;
    shift[c] = sh;
}

// ---------------- graph boundaries ----------------
__global__ void gbounds_kernel(const int* __restrict__ batch, int* __restrict__ gstart, int n) {
    int g = threadIdx.x;
    int lo = 0, hi = n;
    while (lo < hi) {
        int mid = (lo + hi) >> 1;
        if (batch[mid] < g) lo = mid + 1; else hi = mid;
    }
    gstart[g] = lo;
    if (g == 0) gstart[NGRAPH] = n;
}

// ---------------- global add pool (fp16 input) ----------------
__global__ __launch_bounds__(512) void pool_kernel(const __half* __restrict__ a,
                                                   const int* __restrict__ gstart,
                                                   float* __restrict__ g) {
    __shared__ float2 red[512];
    int b = blockIdx.x, tid = threadIdx.x;
    int col2 = tid & 63;
    int rgrp = tid >> 6;
    int lo = gstart[b], hi = gstart[b + 1];
    float2 s = make_float2(0.f, 0.f);
    for (int r = lo + rgrp; r < hi; r += 8) {
        __half2 h = *(const __half2*)&a[(long)r * DP + col2 * 2];
        float2 f = __half22float2(h);
        s.x += f.x; s.y += f.y;
    }
    red[tid] = s;
    __syncthreads();
    if (tid < 64) {
        float2 t = make_float2(0.f, 0.f);
#pragma unroll
        for (int gg = 0; gg < 8; gg++) {
            float2 v = red[gg * 64 + tid];
            t.x += v.x; t.y += v.y;
        }
        *(float2*)&g[b * DP + tid * 2] = t;
    }
}

// ---------------- fused MLP head ----------------
__global__ __launch_bounds__(256) void mlp_kernel(
        const float* __restrict__ g,
        const float* __restrict__ Wf1, const float* __restrict__ bf1,
        const float* __restrict__ Wf2, const float* __restrict__ bf2,
        const float* __restrict__ Wf3, const float* __restrict__ bf3,
        const float* __restrict__ Wf4, const float* __restrict__ bf4,
        float* __restrict__ out) {
    __shared__ float a0[100], a1[200], a2[300], a3[200], red[256];
    int b = blockIdx.x, tid = threadIdx.x;
    if (tid < 100) a0[tid] = g[b * DP + tid];
    __syncthreads();
    for (int c = tid; c < 200; c += 256) {
        float s = bf1[c];
        for (int k = 0; k < 100; k++) s += a0[k] * Wf1[k * 200 + c];
        a1[c] = fmaxf(s, 0.f);
    }
    __syncthreads();
    for (int c = tid; c < 300; c += 256) {
        float s = bf2[c];
        for (int k = 0; k < 200; k++) s += a1[k] * Wf2[k * 300 + c];
        a2[c] = fmaxf(s, 0.f);
    }
    __syncthreads();
    for (int c = tid; c < 200; c += 256) {
        float s = bf3[c];
        for (int k = 0; k < 300; k++) s += a2[k] * Wf3[k * 200 + c];
        a3[c] = fmaxf(s, 0.f);
    }
    __syncthreads();
    red[tid] = (tid < 200) ? a3[tid] * Wf4[tid] : 0.f;
    __syncthreads();
    for (int o = 128; o > 0; o >>= 1) {
        if (tid < o) red[tid] += red[tid + o];
        __syncthreads();
    }
    if (tid == 0) out[b] = red[0] + bf4[0];
}

extern "C" void kernel_launch(void* const* d_in, const int* in_sizes, int n_in,
                              void* d_out, int out_size, void* d_ws, size_t ws_size,
                              hipStream_t stream) {
    const float* x      = (const float*)d_in[0];
    const int*   src    = (const int*)d_in[1];
    const int*   dst    = (const int*)d_in[2];
    const int*   batch  = (const int*)d_in[3];
    const float* W1     = (const float*)d_in[4];
    const float* b1     = (const float*)d_in[5];
    const float* W2     = (const float*)d_in[6];
    const float* b2     = (const float*)d_in[7];
    const float* gamma  = (const float*)d_in[8];
    const float* beta   = (const float*)d_in[9];
    const float* Wa_init= (const float*)d_in[10];
    const float* Wa_root= (const float*)d_in[11];
    const float* ba     = (const float*)d_in[12];
    const float* Wf1    = (const float*)d_in[13];
    const float* bf1    = (const float*)d_in[14];
    const float* Wf2    = (const float*)d_in[15];
    const float* bf2    = (const float*)d_in[16];
    const float* Wf3    = (const float*)d_in[17];
    const float* bf3    = (const float*)d_in[18];
    const float* Wf4    = (const float*)d_in[19];
    const float* bf4    = (const float*)d_in[20];
    float* out = (float*)d_out;

    const int n = NNODES;
    const int e = NEDGES;

    char* ws = (char*)d_ws;
    auto carve = [&](size_t bytes) -> void* {
        void* p = (void*)ws;
        ws += (bytes + 255) & ~(size_t)255;
        return p;
    };
    __half* bufH    = (__half*)carve((size_t)n * DP * 2);
    __half* bufHA   = (__half*)carve((size_t)n * DP * 2);
    __half* bufHB   = (__half*)carve((size_t)n * DP * 2);
    __half* bufR    = (__half*)carve((size_t)n * DP * 2);
    __half* bufHC   = (__half*)carve((size_t)n * DP * 2);
    _Float16* Wt1   = (_Float16*)carve((size_t)DP * DP * 2);
    _Float16* Wt2   = (_Float16*)carve((size_t)DP * DP * 2);
    _Float16* Wt3   = (_Float16*)carve((size_t)DP * DP * 2);
    _Float16* Wt4   = (_Float16*)carve((size_t)DP * DP * 2);
    int*    off     = (int*)carve((size_t)(n + 1) * 4);
    int*    btotal  = (int*)carve((size_t)NBUK * 4);
    int*    bbase   = (int*)carve((size_t)(NBUK + 1) * 4);
    int*    bcursor = (int*)carve((size_t)NBUK * 4);
    int*    ssorted = (int*)carve((size_t)e * 4);
    int2*   gpairs  = (int2*)carve((size_t)e * 8);
    float*  dinv_sl = (float*)carve((size_t)n * 4);
    float*  dinv_nsl= (float*)carve((size_t)n * 4);
    float*  bnsum   = (float*)carve(DP * 4);
    float*  bnsq    = (float*)carve(DP * 4);
    float*  bnscale = (float*)carve(DP * 4);
    float*  bnshift = (float*)carve(DP * 4);
    int*    gstart  = (int*)carve((size_t)(NGRAPH + 1) * 4);
    float*  gpool   = (float*)carve((size_t)NGRAPH * DP * 4);

    const int nchunk = (e + BINCH - 1) / BINCH;

    // ---- pack all weights (one launch) ----
    packW4_kernel<<<256, 256, 0, stream>>>(W1, W2, Wa_init, Wa_root, Wt1, Wt2, Wt3, Wt4);

    // ---- build CSR by dst ----
    hipMemsetAsync(btotal, 0, (size_t)NBUK * 4, stream);
    hipMemsetAsync(bnsum, 0, DP * 4, stream);
    hipMemsetAsync(bnsq, 0, DP * 4, stream);
    bin_count_kernel<<<nchunk, 256, 0, stream>>>(dst, btotal, e);
    bucket_scan_kernel<<<1, 512, 0, stream>>>(btotal, bbase, bcursor, e);
    bin_kernel<<<nchunk, 256, 0, stream>>>(src, dst, bcursor, gpairs, e);
    bucket_build_kernel<<<NBUK, 256, 0, stream>>>(gpairs, bbase, off, ssorted, dinv_sl, dinv_nsl, n, e);
    gbounds_kernel<<<1, 512, 0, stream>>>(batch, gstart, n);

    const int prop_blocks = (n + 3) / 4;
    const int mm_blocks = (n + 63) / 64;

    // ---- SGConv 1 ----
    prescale_kernel<<<(int)(((long)n * 32 + 255) / 256), 256, 0, stream>>>(x, dinv_sl, bufH, n);
    prop_kernel<<<prop_blocks, 256, 0, stream>>>(bufH, ssorted, off, dinv_sl, bufHA, n, 1);
    matmul_mfma_kernel<<<mm_blocks, 256, 0, stream>>>(bufHA, Wt1, b1, dinv_sl, bufH, nullptr, nullptr, n, DIM, 1);

    // ---- SGConv 2 (+fused BN stats) ----
    prop_kernel<<<prop_blocks, 256, 0, stream>>>(bufH, ssorted, off, dinv_sl, bufHA, n, 1);
    matmul_mfma_kernel<<<mm_blocks, 256, 0, stream>>>(bufHA, Wt2, b2, nullptr, bufHB, bnsum, bnsq, n, DIM, 1);

    // ---- BatchNorm params (apply fused into dual's A-load) ----
    bn_prep_kernel<<<1, 128, 0, stream>>>(bnsum, bnsq, gamma, beta, bnscale, bnshift, n);

    // ---- ARMAConv: dual matmul with fused BN, then prop with fused add+relu ----
    matmul_dual_kernel<<<mm_blocks, 256, 0, stream>>>(bufHB, Wt3, Wt4, ba, dinv_nsl, bnscale, bnshift, bufH, bufR, n, DIM);
    prop_arma_kernel<<<prop_blocks, 256, 0, stream>>>(bufH, ssorted, off, dinv_nsl, bufR, bufHC, n);

    // ---- global add pool ----
    pool_kernel<<<NGRAPH, 512, 0, stream>>>(bufHC, gstart, gpool);

    // ---- MLP head ----
    mlp_kernel<<<NGRAPH, 256, 0, stream>>>(gpool, Wf1, bf1, Wf2, bf2, Wf3, bf3, Wf4, bf4, out);
}